// Round 2
// baseline (218.977 us; speedup 1.0000x reference)
//
#include <hip/hip_runtime.h>
#include <stdint.h>

// SVDQuant forward on MI355X:
//   y = Q4(x*smooth) @ Q4(Wres)^T + (x*smooth) @ lora_down @ lora_up^T + bias
// R6 structure (3 kernels):
//   K0 ldt_kernel (grid 256): ldT[32][2048] = bf16(lora_down^T)
//   K1 prep_kernel (grid 2560):
//     blocks [0,512):   16 x-rows each. Phase A: coalesced fakequant(x*smooth)
//                       -> Xcat[:,0:2048] + bf16 x_s in LDS. Phase B: rank-32 MFMA
//                       t = x_s @ lora_down (B-frags = short8 loads from ldT)
//                       -> Xcat[:,2048:2080]; pad [2080:2112)=0.
//     blocks [512,2560): 1 w-row each: Wcat[:,0:2048]=fakequant(Wres),
//                       [2048:2080)=bf16(lora_up), [2080:2112)=0.
//   K2 gemm_kernel: out = Xcat @ Wcat^T + bias, K=2112 = 33x64.
//     m201-style 8-phase schedule: 256x256 tile, BK=64, 512 thr (8 waves 2Mx4N,
//     wave-tile 128x64), 2x64KB LDS dbuf, 4 phases/K-tile each
//     {ds_read subtile; s_barrier; setprio(1); 16 MFMA; setprio(0); s_barrier},
//     boundary: barrier -> STAGE(t+2) -> vmcnt(8) (t+2's loads stay in flight
//     across barriers, never drain) -> barrier. chunk^=(row&7) XOR swizzle
//     (pre-swizzled global source + swizzled ds_read), XCD-chunked blockIdx.

typedef __attribute__((ext_vector_type(8))) short short8;
typedef __attribute__((ext_vector_type(8))) unsigned short ushort8;
typedef __attribute__((ext_vector_type(4))) unsigned short ushort4v;
typedef __attribute__((ext_vector_type(4))) float floatx4;

#define M_TOK 8192
#define K_IN  2048
#define N_OUT 2048
#define RANK  32
#define KC    2112      // 2048 quant + 32 lowrank + 32 zero pad = 33 * 64
#define NTILE 33        // K-tiles of 64
#define XS_STRIDE 2056  // LDS x_s row stride (shorts): +8 -> 4-bank row rotation

// round-to-nearest-even f32 -> bf16 (finite inputs only)
__device__ __forceinline__ unsigned short f2bf(float f) {
  unsigned int u = __float_as_uint(f);
  u += 0x7fff + ((u >> 16) & 1);
  return (unsigned short)(u >> 16);
}

// fakequant 8 values held by this lane; group of 64 = 8 consecutive lanes
__device__ __forceinline__ void quant8(const float* v, unsigned short* q) {
  float amax = 0.f;
#pragma unroll
  for (int i = 0; i < 8; ++i) amax = fmaxf(amax, fabsf(v[i]));
  amax = fmaxf(amax, __shfl_xor(amax, 1, 64));
  amax = fmaxf(amax, __shfl_xor(amax, 2, 64));
  amax = fmaxf(amax, __shfl_xor(amax, 4, 64));
  float scale = fmaxf(amax / 7.0f, 1e-8f);
#pragma unroll
  for (int i = 0; i < 8; ++i) {
    float qq = rintf(v[i] / scale);   // IEEE div + RNE == jnp.round(g/scale)
    qq = fminf(fmaxf(qq, -7.f), 7.f);
    q[i] = f2bf(qq * scale);
  }
}

// ---------------- K0: ldT = bf16(lora_down^T), [32][2048] -------------------
__global__ __launch_bounds__(256) void ldt_kernel(const float* __restrict__ ld,
                                                  unsigned short* __restrict__ ldT) {
  int g = blockIdx.x * 256 + threadIdx.x;   // 65536 elements, 1 per thread
  int r = g >> 11, kk = g & 2047;
  ldT[(size_t)r * 2048 + kk] = f2bf(ld[(size_t)kk * RANK + r]);
}

// ---------------- K1: fused prep --------------------------------------------
__global__ __launch_bounds__(256) void prep_kernel(const float* __restrict__ x,
                                                   const float* __restrict__ smooth,
                                                   const float* __restrict__ wgt,
                                                   const unsigned short* __restrict__ ldT,
                                                   const float* __restrict__ lup,
                                                   unsigned short* __restrict__ Xcat,
                                                   unsigned short* __restrict__ Wcat) {
  __shared__ unsigned short xs[16 * XS_STRIDE];  // 64.25 KiB bf16 x_s
  __shared__ float red[4][16][32];               // 8 KiB
  int tid = threadIdx.x;

  if (blockIdx.x >= 512) {
    // ---- W path: one row of Wres per block ----
    int row = blockIdx.x - 512;
    const float4* wr = (const float4*)(wgt + (size_t)row * K_IN);
    float4 a0 = wr[tid * 2], a1 = wr[tid * 2 + 1];
    float v[8] = {a0.x, a0.y, a0.z, a0.w, a1.x, a1.y, a1.z, a1.w};
    ushort8 q;
    quant8(v, (unsigned short*)&q);
    *(ushort8*)(Wcat + (size_t)row * KC + tid * 8) = q;
    if (tid < 32)      Wcat[(size_t)row * KC + 2048 + tid] = f2bf(lup[row * RANK + tid]);
    else if (tid < 64) Wcat[(size_t)row * KC + 2048 + tid] = 0;
    return;
  }

  // ---- X path: 16 rows per block ----
  int rowbase = blockIdx.x * 16;
  int w = tid >> 6, lane = tid & 63, quad = lane >> 4, l16 = lane & 15;

  // Phase A: coalesced quantize, one row per pass (256 thr x 8 elems = 2048)
  const float4* sr = (const float4*)smooth;
  float4 s0 = sr[tid * 2], s1 = sr[tid * 2 + 1];
#pragma unroll 2
  for (int r = 0; r < 16; ++r) {
    const float4* xr = (const float4*)(x + (size_t)(rowbase + r) * K_IN);
    float4 a0 = xr[tid * 2], a1 = xr[tid * 2 + 1];
    float v[8] = {a0.x * s0.x, a0.y * s0.y, a0.z * s0.z, a0.w * s0.w,
                  a1.x * s1.x, a1.y * s1.y, a1.z * s1.z, a1.w * s1.w};
    ushort8 q;
    quant8(v, (unsigned short*)&q);
    *(ushort8*)(Xcat + (size_t)(rowbase + r) * KC + tid * 8) = q;
    ushort8 sb;
#pragma unroll
    for (int t = 0; t < 8; ++t) sb[t] = f2bf(v[t]);
    *(ushort8*)(xs + r * XS_STRIDE + tid * 8) = sb;
  }
  // zero pad Xcat[:, 2080:2112): 16 threads x 4B per row
  *(unsigned int*)(Xcat + (size_t)(rowbase + (tid >> 4)) * KC + 2080 + (tid & 15) * 2) = 0u;
  __syncthreads();

  // Phase B: t = x_s @ lora_down. wave w covers k in [w*512, w*512+512).
  floatx4 acc[2];
  acc[0] = (floatx4)0.f;
  acc[1] = (floatx4)0.f;
  int kbase = w * 512;
#pragma unroll 2
  for (int it = 0; it < 16; ++it) {
    int k = kbase + it * 32 + quad * 8;
    short8 af = *(const short8*)(xs + l16 * XS_STRIDE + k);
    // B-frag: B[k=quad*8+j][n=l16 (+16)] = ldT[n][k..k+7] -- one 16B load each
    short8 b0 = *(const short8*)(ldT + (size_t)l16 * 2048 + k);
    short8 b1 = *(const short8*)(ldT + (size_t)(16 + l16) * 2048 + k);
    acc[0] = __builtin_amdgcn_mfma_f32_16x16x32_bf16(af, b0, acc[0], 0, 0, 0);
    acc[1] = __builtin_amdgcn_mfma_f32_16x16x32_bf16(af, b1, acc[1], 0, 0, 0);
  }
  // C layout: row = quad*4 + r, col = l16 (+16 for acc[1])
#pragma unroll
  for (int nt = 0; nt < 2; ++nt)
#pragma unroll
    for (int r = 0; r < 4; ++r)
      red[w][quad * 4 + r][nt * 16 + l16] = acc[nt][r];
  __syncthreads();
  if (tid < 128) {
    int rl = tid >> 3, seg = tid & 7;  // row 0..15, col segment of 4
    ushort4v o;
#pragma unroll
    for (int j = 0; j < 4; ++j) {
      int c = seg * 4 + j;
      float s = red[0][rl][c] + red[1][rl][c] + red[2][rl][c] + red[3][rl][c];
      o[j] = f2bf(s);
    }
    *(ushort4v*)(Xcat + (size_t)(rowbase + rl) * KC + 2048 + seg * 4) = o;
  }
}

// ---------------- K2: main GEMM: out = Xcat @ Wcat^T + bias ----------------
__device__ __forceinline__ void gld_lds16(const unsigned short* g, unsigned short* l) {
  __builtin_amdgcn_global_load_lds(
      (const __attribute__((address_space(1))) unsigned int*)g,
      (__attribute__((address_space(3))) unsigned int*)l, 16, 0, 0);
}

__global__ __launch_bounds__(512) void gemm_kernel(const unsigned short* __restrict__ Xcat,
                                                   const unsigned short* __restrict__ Wcat,
                                                   const float* __restrict__ bias,
                                                   float* __restrict__ out) {
  // 2 K-tile buffers x (A 256x64 + B 256x64) bf16 = 128 KiB, 1 block/CU
  __shared__ unsigned short smem[65536];
  int tid = threadIdx.x;
  int w = tid >> 6, lane = tid & 63, quad = lane >> 4, l16 = lane & 15;
  int wm = w >> 2, wn = w & 3;  // 2 M-waves x 4 N-waves; wave tile 128x64

  // Bijective XCD chunking: grid 256 = 8 XCDs x 32; each XCD gets a contiguous
  // chunk = 4 M-panels x 8 N-panels -> A/B panel slabs stay L2-resident.
  int bid = blockIdx.x;
  int wg = (bid & 7) * 32 + (bid >> 3);
  int bM = (wg >> 3) * 256;
  int bN = (wg & 7) * 256;

  // Staging: per K-tile, A = 256 rows x 8 chunks(16B) = 32KB (same B).
  // thread covers (row = 64*i + tid/8, chunk slot = tid&7) for i=0..3; source
  // chunk pre-swizzled with row&7 == (tid>>3)&7 so swizzled ds_reads see it.
  int srow = tid >> 3;                  // 0..63
  int csrc = (tid & 7) ^ (srow & 7);
  const unsigned short* Ag = Xcat + (size_t)(bM + srow) * KC + csrc * 8;
  const unsigned short* Bg = Wcat + (size_t)(bN + srow) * KC + csrc * 8;
  int ldsrow = w * 512;                 // wave-uniform dest: w*8 rows * 64 shorts

#define STAGE(tt, OFF)                                                        \
  do {                                                                        \
    int k0_ = (tt) * 64;                                                      \
    gld_lds16(Ag + k0_,            smem + (OFF) + ldsrow);                    \
    gld_lds16(Ag + 64 * KC + k0_,  smem + (OFF) + 4096 + ldsrow);             \
    gld_lds16(Ag + 128 * KC + k0_, smem + (OFF) + 8192 + ldsrow);             \
    gld_lds16(Ag + 192 * KC + k0_, smem + (OFF) + 12288 + ldsrow);            \
    gld_lds16(Bg + k0_,            smem + (OFF) + 16384 + ldsrow);            \
    gld_lds16(Bg + 64 * KC + k0_,  smem + (OFF) + 20480 + ldsrow);            \
    gld_lds16(Bg + 128 * KC + k0_, smem + (OFF) + 24576 + ldsrow);            \
    gld_lds16(Bg + 192 * KC + k0_, smem + (OFF) + 28672 + ldsrow);            \
  } while (0)

  // fragment LDS offsets (shorts): row*64 + swizzled chunk; row&7 == l16&7.
  int l7 = l16 & 7;
  int ck0 = (quad ^ l7) * 8;            // kk = 0 chunk
  int ck1 = ((4 + quad) ^ l7) * 8;      // kk = 1 chunk
  int aoff[8], boff[4];
#pragma unroll
  for (int mt = 0; mt < 8; ++mt) aoff[mt] = (wm * 128 + mt * 16 + l16) * 64;
#pragma unroll
  for (int nt = 0; nt < 4; ++nt) boff[nt] = 16384 + (wn * 64 + nt * 16 + l16) * 64;

  floatx4 acc[8][4];
#pragma unroll
  for (int mt = 0; mt < 8; ++mt)
#pragma unroll
    for (int nt = 0; nt < 4; ++nt) acc[mt][nt] = (floatx4)0.f;

  // prologue: tiles 0,1 staged; certify tile 0 (8 newest stay in flight)
  STAGE(0, 0);
  STAGE(1, 32768);
  asm volatile("s_waitcnt vmcnt(8)" ::: "memory");
  __builtin_amdgcn_s_barrier();

#pragma unroll 1
  for (int t = 0; t < NTILE; ++t) {
    unsigned short* sb = smem + (t & 1) * 32768;
    short8 a[4], b0[4], b1[4];

    // ---- phase 0: (mt 0-3, kk 0) ----
#pragma unroll
    for (int mt = 0; mt < 4; ++mt) a[mt] = *(const short8*)(sb + aoff[mt] + ck0);
#pragma unroll
    for (int nt = 0; nt < 4; ++nt) b0[nt] = *(const short8*)(sb + boff[nt] + ck0);
    __builtin_amdgcn_s_barrier();
    __builtin_amdgcn_s_setprio(1);
#pragma unroll
    for (int mt = 0; mt < 4; ++mt)
#pragma unroll
      for (int nt = 0; nt < 4; ++nt)
        acc[mt][nt] = __builtin_amdgcn_mfma_f32_16x16x32_bf16(a[mt], b0[nt], acc[mt][nt], 0, 0, 0);
    __builtin_amdgcn_s_setprio(0);
    __builtin_amdgcn_s_barrier();

    // ---- phase 1: (mt 0-3, kk 1) ----
#pragma unroll
    for (int mt = 0; mt < 4; ++mt) a[mt] = *(const short8*)(sb + aoff[mt] + ck1);
#pragma unroll
    for (int nt = 0; nt < 4; ++nt) b1[nt] = *(const short8*)(sb + boff[nt] + ck1);
    __builtin_amdgcn_s_barrier();
    __builtin_amdgcn_s_setprio(1);
#pragma unroll
    for (int mt = 0; mt < 4; ++mt)
#pragma unroll
      for (int nt = 0; nt < 4; ++nt)
        acc[mt][nt] = __builtin_amdgcn_mfma_f32_16x16x32_bf16(a[mt], b1[nt], acc[mt][nt], 0, 0, 0);
    __builtin_amdgcn_s_setprio(0);
    __builtin_amdgcn_s_barrier();

    // ---- phase 2: (mt 4-7, kk 0), reuse b0 ----
#pragma unroll
    for (int mt = 0; mt < 4; ++mt) a[mt] = *(const short8*)(sb + aoff[mt + 4] + ck0);
    __builtin_amdgcn_s_barrier();
    __builtin_amdgcn_s_setprio(1);
#pragma unroll
    for (int mt = 0; mt < 4; ++mt)
#pragma unroll
      for (int nt = 0; nt < 4; ++nt)
        acc[mt + 4][nt] = __builtin_amdgcn_mfma_f32_16x16x32_bf16(a[mt], b0[nt], acc[mt + 4][nt], 0, 0, 0);
    __builtin_amdgcn_s_setprio(0);
    __builtin_amdgcn_s_barrier();

    // ---- phase 3: (mt 4-7, kk 1), reuse b1 ----
#pragma unroll
    for (int mt = 0; mt < 4; ++mt) a[mt] = *(const short8*)(sb + aoff[mt + 4] + ck1);
    __builtin_amdgcn_s_barrier();
    __builtin_amdgcn_s_setprio(1);
#pragma unroll
    for (int mt = 0; mt < 4; ++mt)
#pragma unroll
      for (int nt = 0; nt < 4; ++nt)
        acc[mt + 4][nt] = __builtin_amdgcn_mfma_f32_16x16x32_bf16(a[mt], b1[nt], acc[mt + 4][nt], 0, 0, 0);
    __builtin_amdgcn_s_setprio(0);
    __builtin_amdgcn_s_barrier();  // all waves done reading buffer t&1

    // ---- tile boundary: refill the just-freed buffer, counted wait ----
    if (t + 2 < NTILE) {
      STAGE(t + 2, (t & 1) * 32768);               // 8 loads into freed buffer
      asm volatile("s_waitcnt vmcnt(8)" ::: "memory");  // tile t+1 landed
    } else if (t == NTILE - 2) {
      asm volatile("s_waitcnt vmcnt(0)" ::: "memory");  // last tile landed
    }
    __builtin_amdgcn_s_barrier();  // everyone's next tile visible
  }
#undef STAGE

  // epilogue: + bias, store fp32
#pragma unroll
  for (int nt = 0; nt < 4; ++nt) {
    int col = bN + wn * 64 + nt * 16 + l16;
    float bv = bias[col];
#pragma unroll
    for (int mt = 0; mt < 8; ++mt) {
      int row = bM + wm * 128 + mt * 16 + quad * 4;
#pragma unroll
      for (int r2 = 0; r2 < 4; ++r2)
        out[(size_t)(row + r2) * N_OUT + col] = acc[mt][nt][r2] + bv;
    }
  }
}

extern "C" void kernel_launch(void* const* d_in, const int* in_sizes, int n_in,
                              void* d_out, int out_size, void* d_ws, size_t ws_size,
                              hipStream_t stream) {
  const float* x      = (const float*)d_in[0];
  const float* wgt    = (const float*)d_in[1];
  const float* ld     = (const float*)d_in[2];
  const float* lup    = (const float*)d_in[3];
  const float* smooth = (const float*)d_in[4];
  const float* bias   = (const float*)d_in[5];
  float* out = (float*)d_out;

  unsigned short* Xcat = (unsigned short*)d_ws;                 // 8192*2112*2 = 34.6 MB
  unsigned short* Wcat = Xcat + (size_t)M_TOK * KC;             //  8.65 MB
  unsigned short* ldT  = Wcat + (size_t)N_OUT * KC;             //  128 KB

  hipLaunchKernelGGL(ldt_kernel, dim3(256), dim3(256), 0, stream, ld, ldT);
  hipLaunchKernelGGL(prep_kernel, dim3(512 + N_OUT), dim3(256), 0, stream,
                     x, smooth, wgt, ldT, lup, Xcat, Wcat);
  hipLaunchKernelGGL(gemm_kernel, dim3((M_TOK / 256) * (N_OUT / 256)), dim3(512), 0, stream,
                     Xcat, Wcat, bias, out);
}

// Round 3
// 218.774 us; speedup vs baseline: 1.0009x; 1.0009x over previous
//
#include <hip/hip_runtime.h>
#include <stdint.h>

// SVDQuant forward on MI355X:
//   y = Q4(x*smooth) @ Q4(Wres)^T + (x*smooth) @ lora_down @ lora_up^T + bias
// R7 structure (4 kernels):
//   K0 ldt_kernel (grid 256): ldT[32][2048] = bf16(lora_down^T)
//   K1 wprep_kernel (grid 2048, NO LDS -> high occupancy): 1 w-row each:
//      Wcat[:,0:2048]=fakequant(Wres), [2048:2080)=bf16(lora_up), [2080:2112)=0.
//   K2 xprep_kernel (grid 512): 16 x-rows each. Phase A: coalesced
//      fakequant(x*smooth) -> Xcat[:,0:2048] + bf16 x_s in LDS. Phase B:
//      rank-32 MFMA t = x_s @ lora_down -> Xcat[:,2048:2080]; pad = 0.
//   K3 gemm_kernel: out = Xcat @ Wcat^T + bias, K=2112 = 66x32.
//     256x256 tile, BK=32, 512 thr (8 waves 2Mx4N, wave-tile 128x64),
//     3-buffer LDS ring (96 KiB), 2 phases/K-tile, FINE INTERLEAVE (m196):
//     each phase = {ds_read frags; issue 2 of tile t+2's 4 staging loads;
//     barrier; setprio(1); 16 MFMA; setprio(0); barrier}; one counted
//     vmcnt(4) per tile end (t+2's loads stay in flight across barriers).
//     2-way-max chunk swizzle (pre-swizzled source + swizzled ds_read),
//     XCD-chunked blockIdx.

typedef __attribute__((ext_vector_type(8))) short short8;
typedef __attribute__((ext_vector_type(8))) unsigned short ushort8;
typedef __attribute__((ext_vector_type(4))) unsigned short ushort4v;
typedef __attribute__((ext_vector_type(4))) float floatx4;

#define M_TOK 8192
#define K_IN  2048
#define N_OUT 2048
#define RANK  32
#define KC    2112      // 2048 quant + 32 lowrank + 32 zero pad = 66 * 32
#define NTILE 66        // K-tiles of 32
#define XS_STRIDE 2056  // LDS x_s row stride (shorts): +8 -> 4-bank row rotation

// round-to-nearest-even f32 -> bf16 (finite inputs only)
__device__ __forceinline__ unsigned short f2bf(float f) {
  unsigned int u = __float_as_uint(f);
  u += 0x7fff + ((u >> 16) & 1);
  return (unsigned short)(u >> 16);
}

// fakequant 8 values held by this lane; group of 64 = 8 consecutive lanes
__device__ __forceinline__ void quant8(const float* v, unsigned short* q) {
  float amax = 0.f;
#pragma unroll
  for (int i = 0; i < 8; ++i) amax = fmaxf(amax, fabsf(v[i]));
  amax = fmaxf(amax, __shfl_xor(amax, 1, 64));
  amax = fmaxf(amax, __shfl_xor(amax, 2, 64));
  amax = fmaxf(amax, __shfl_xor(amax, 4, 64));
  float scale = fmaxf(amax / 7.0f, 1e-8f);
#pragma unroll
  for (int i = 0; i < 8; ++i) {
    float qq = rintf(v[i] / scale);   // IEEE div + RNE == jnp.round(g/scale)
    qq = fminf(fmaxf(qq, -7.f), 7.f);
    q[i] = f2bf(qq * scale);
  }
}

// ---------------- K0: ldT = bf16(lora_down^T), [32][2048] -------------------
__global__ __launch_bounds__(256) void ldt_kernel(const float* __restrict__ ld,
                                                  unsigned short* __restrict__ ldT) {
  int g = blockIdx.x * 256 + threadIdx.x;   // 65536 elements, 1 per thread
  int r = g >> 11, kk = g & 2047;
  ldT[(size_t)r * 2048 + kk] = f2bf(ld[(size_t)kk * RANK + r]);
}

// ---------------- K1: W prep (no LDS) ---------------------------------------
__global__ __launch_bounds__(256) void wprep_kernel(const float* __restrict__ wgt,
                                                    const float* __restrict__ lup,
                                                    unsigned short* __restrict__ Wcat) {
  int tid = threadIdx.x;
  int row = blockIdx.x;
  const float4* wr = (const float4*)(wgt + (size_t)row * K_IN);
  float4 a0 = wr[tid * 2], a1 = wr[tid * 2 + 1];
  float v[8] = {a0.x, a0.y, a0.z, a0.w, a1.x, a1.y, a1.z, a1.w};
  ushort8 q;
  quant8(v, (unsigned short*)&q);
  *(ushort8*)(Wcat + (size_t)row * KC + tid * 8) = q;
  if (tid < 32)      Wcat[(size_t)row * KC + 2048 + tid] = f2bf(lup[row * RANK + tid]);
  else if (tid < 64) Wcat[(size_t)row * KC + 2048 + tid] = 0;
}

// ---------------- K2: X prep ------------------------------------------------
__global__ __launch_bounds__(256) void xprep_kernel(const float* __restrict__ x,
                                                    const float* __restrict__ smooth,
                                                    const unsigned short* __restrict__ ldT,
                                                    unsigned short* __restrict__ Xcat) {
  __shared__ unsigned short xs[16 * XS_STRIDE];  // 64.25 KiB bf16 x_s
  __shared__ float red[4][16][32];               // 8 KiB
  int tid = threadIdx.x;
  int rowbase = blockIdx.x * 16;
  int w = tid >> 6, lane = tid & 63, quad = lane >> 4, l16 = lane & 15;

  // Phase A: coalesced quantize, one row per pass (256 thr x 8 elems = 2048)
  const float4* sr = (const float4*)smooth;
  float4 s0 = sr[tid * 2], s1 = sr[tid * 2 + 1];
#pragma unroll 4
  for (int r = 0; r < 16; ++r) {
    const float4* xr = (const float4*)(x + (size_t)(rowbase + r) * K_IN);
    float4 a0 = xr[tid * 2], a1 = xr[tid * 2 + 1];
    float v[8] = {a0.x * s0.x, a0.y * s0.y, a0.z * s0.z, a0.w * s0.w,
                  a1.x * s1.x, a1.y * s1.y, a1.z * s1.z, a1.w * s1.w};
    ushort8 q;
    quant8(v, (unsigned short*)&q);
    *(ushort8*)(Xcat + (size_t)(rowbase + r) * KC + tid * 8) = q;
    ushort8 sb;
#pragma unroll
    for (int t = 0; t < 8; ++t) sb[t] = f2bf(v[t]);
    *(ushort8*)(xs + r * XS_STRIDE + tid * 8) = sb;
  }
  // zero pad Xcat[:, 2080:2112): 16 threads x 4B per row
  *(unsigned int*)(Xcat + (size_t)(rowbase + (tid >> 4)) * KC + 2080 + (tid & 15) * 2) = 0u;
  __syncthreads();

  // Phase B: t = x_s @ lora_down. wave w covers k in [w*512, w*512+512).
  floatx4 acc[2];
  acc[0] = (floatx4)0.f;
  acc[1] = (floatx4)0.f;
  int kbase = w * 512;
#pragma unroll 2
  for (int it = 0; it < 16; ++it) {
    int k = kbase + it * 32 + quad * 8;
    short8 af = *(const short8*)(xs + l16 * XS_STRIDE + k);
    // B-frag: B[k=quad*8+j][n=l16 (+16)] = ldT[n][k..k+7] -- one 16B load each
    short8 b0 = *(const short8*)(ldT + (size_t)l16 * 2048 + k);
    short8 b1 = *(const short8*)(ldT + (size_t)(16 + l16) * 2048 + k);
    acc[0] = __builtin_amdgcn_mfma_f32_16x16x32_bf16(af, b0, acc[0], 0, 0, 0);
    acc[1] = __builtin_amdgcn_mfma_f32_16x16x32_bf16(af, b1, acc[1], 0, 0, 0);
  }
  // C layout: row = quad*4 + r, col = l16 (+16 for acc[1])
#pragma unroll
  for (int nt = 0; nt < 2; ++nt)
#pragma unroll
    for (int r = 0; r < 4; ++r)
      red[w][quad * 4 + r][nt * 16 + l16] = acc[nt][r];
  __syncthreads();
  if (tid < 128) {
    int rl = tid >> 3, seg = tid & 7;  // row 0..15, col segment of 4
    ushort4v o;
#pragma unroll
    for (int j = 0; j < 4; ++j) {
      int c = seg * 4 + j;
      float s = red[0][rl][c] + red[1][rl][c] + red[2][rl][c] + red[3][rl][c];
      o[j] = f2bf(s);
    }
    *(ushort4v*)(Xcat + (size_t)(rowbase + rl) * KC + 2048 + seg * 4) = o;
  }
}

// ---------------- K3: main GEMM: out = Xcat @ Wcat^T + bias ----------------
__device__ __forceinline__ void gld_lds16(const unsigned short* g, unsigned short* l) {
  __builtin_amdgcn_global_load_lds(
      (const __attribute__((address_space(1))) unsigned int*)g,
      (__attribute__((address_space(3))) unsigned int*)l, 16, 0, 0);
}

__global__ __launch_bounds__(512) void gemm_kernel(const unsigned short* __restrict__ Xcat,
                                                   const unsigned short* __restrict__ Wcat,
                                                   const float* __restrict__ bias,
                                                   float* __restrict__ out) {
  // ring of 3 K-tile buffers x (A 256x32 + B 256x32) bf16 = 96 KiB
  __shared__ unsigned short smem[49152];
  int tid = threadIdx.x;
  int w = tid >> 6, lane = tid & 63, quad = lane >> 4, l16 = lane & 15;
  int wm = w >> 2, wn = w & 3;  // 2 M-waves x 4 N-waves; wave tile 128x64

  // Bijective XCD chunking: grid 256 = 8 XCDs x 32; each XCD gets a contiguous
  // chunk = 4 M-panels x 8 N-panels -> A/B panel slabs stay L2-resident.
  int bid = blockIdx.x;
  int wg = (bid & 7) * 32 + (bid >> 3);
  int bM = (wg >> 3) * 256;
  int bN = (wg & 7) * 256;

  // Staging: per K-tile, A = 256 rows x 4 chunks(16B) = 16KB = 2 load rounds
  // (rows 0-127 / 128-255), same for B -> 4 loads per tile, 2 issued per phase.
  // thread covers (row = tid/4, chunk slot = tid&3); source chunk pre-swizzled
  // with (row>>1)&3 == (tid>>3)&3 so swizzled ds_reads see linear data.
  int srow = tid >> 2;                  // 0..127
  int csrc = (tid & 3) ^ ((tid >> 3) & 3);
  const unsigned short* Ag = Xcat + (size_t)(bM + srow) * KC + csrc * 8;
  const unsigned short* Bg = Wcat + (size_t)(bN + srow) * KC + csrc * 8;
  int ldsw = w * 512;                   // wave-uniform dest: lane*16B within

  // fragment LDS offsets (shorts): row*32 + swizzled chunk; (row>>1)&3 == (l16>>1)&3
  int ck = (quad ^ ((l16 >> 1) & 3)) * 8;
  int aoff[8], boff[4];
#pragma unroll
  for (int mt = 0; mt < 8; ++mt) aoff[mt] = (wm * 128 + mt * 16 + l16) * 32 + ck;
#pragma unroll
  for (int nt = 0; nt < 4; ++nt) boff[nt] = 8192 + (wn * 64 + nt * 16 + l16) * 32 + ck;

  floatx4 acc[8][4];
#pragma unroll
  for (int mt = 0; mt < 8; ++mt)
#pragma unroll
    for (int nt = 0; nt < 4; ++nt) acc[mt][nt] = (floatx4)0.f;

  int b0 = 0, b1 = 16384, b2 = 32768;   // ring: read b0, next b1, stage into b2

#define STAGE_A(tt, OFF)                                                      \
  do {                                                                        \
    int k0_ = (tt) * 32;                                                      \
    gld_lds16(Ag + k0_,           smem + (OFF) + ldsw);                       \
    gld_lds16(Ag + 128 * KC + k0_, smem + (OFF) + 4096 + ldsw);               \
  } while (0)
#define STAGE_B(tt, OFF)                                                      \
  do {                                                                        \
    int k0_ = (tt) * 32;                                                      \
    gld_lds16(Bg + k0_,           smem + (OFF) + 8192 + ldsw);                \
    gld_lds16(Bg + 128 * KC + k0_, smem + (OFF) + 12288 + ldsw);              \
  } while (0)

  // prologue: tiles 0,1 fully staged; certify tile 0 (4 newest stay in flight)
  STAGE_A(0, 0);
  STAGE_B(0, 0);
  STAGE_A(1, 16384);
  STAGE_B(1, 16384);
  asm volatile("s_waitcnt vmcnt(4)" ::: "memory");
  __builtin_amdgcn_s_barrier();

#pragma unroll 1
  for (int t = 0; t < NTILE; ++t) {
    unsigned short* sb = smem + b0;
    short8 a[4], b[4];

    // ---- phase 0: mt 0-3 x nt 0-3; interleave A-staging of tile t+2 ----
#pragma unroll
    for (int mt = 0; mt < 4; ++mt) a[mt] = *(const short8*)(sb + aoff[mt]);
#pragma unroll
    for (int nt = 0; nt < 4; ++nt) b[nt] = *(const short8*)(sb + boff[nt]);
    if (t + 2 < NTILE) STAGE_A(t + 2, b2);
    __builtin_amdgcn_s_barrier();
    __builtin_amdgcn_s_setprio(1);
#pragma unroll
    for (int mt = 0; mt < 4; ++mt)
#pragma unroll
      for (int nt = 0; nt < 4; ++nt)
        acc[mt][nt] = __builtin_amdgcn_mfma_f32_16x16x32_bf16(a[mt], b[nt], acc[mt][nt], 0, 0, 0);
    __builtin_amdgcn_s_setprio(0);
    __builtin_amdgcn_s_barrier();

    // ---- phase 1: mt 4-7 x nt 0-3 (reuse b); interleave B-staging ----
#pragma unroll
    for (int mt = 0; mt < 4; ++mt) a[mt] = *(const short8*)(sb + aoff[mt + 4]);
    if (t + 2 < NTILE) STAGE_B(t + 2, b2);
    __builtin_amdgcn_s_barrier();
    __builtin_amdgcn_s_setprio(1);
#pragma unroll
    for (int mt = 0; mt < 4; ++mt)
#pragma unroll
      for (int nt = 0; nt < 4; ++nt)
        acc[mt + 4][nt] = __builtin_amdgcn_mfma_f32_16x16x32_bf16(a[mt], b[nt], acc[mt + 4][nt], 0, 0, 0);
    __builtin_amdgcn_s_setprio(0);

    // ---- tile end: certify tile t+1 landed; t+2's 4 stay in flight ----
    if (t < NTILE - 2)
      asm volatile("s_waitcnt vmcnt(4)" ::: "memory");
    else if (t == NTILE - 2)
      asm volatile("s_waitcnt vmcnt(0)" ::: "memory");
    __builtin_amdgcn_s_barrier();
    int tmp = b0; b0 = b1; b1 = b2; b2 = tmp;
  }
#undef STAGE_A
#undef STAGE_B

  // epilogue: + bias, store fp32
#pragma unroll
  for (int nt = 0; nt < 4; ++nt) {
    int col = bN + wn * 64 + nt * 16 + l16;
    float bv = bias[col];
#pragma unroll
    for (int mt = 0; mt < 8; ++mt) {
      int row = bM + wm * 128 + mt * 16 + quad * 4;
#pragma unroll
      for (int r2 = 0; r2 < 4; ++r2)
        out[(size_t)(row + r2) * N_OUT + col] = acc[mt][nt][r2] + bv;
    }
  }
}

extern "C" void kernel_launch(void* const* d_in, const int* in_sizes, int n_in,
                              void* d_out, int out_size, void* d_ws, size_t ws_size,
                              hipStream_t stream) {
  const float* x      = (const float*)d_in[0];
  const float* wgt    = (const float*)d_in[1];
  const float* ld     = (const float*)d_in[2];
  const float* lup    = (const float*)d_in[3];
  const float* smooth = (const float*)d_in[4];
  const float* bias   = (const float*)d_in[5];
  float* out = (float*)d_out;

  unsigned short* Xcat = (unsigned short*)d_ws;                 // 8192*2112*2 = 34.6 MB
  unsigned short* Wcat = Xcat + (size_t)M_TOK * KC;             //  8.65 MB
  unsigned short* ldT  = Wcat + (size_t)N_OUT * KC;             //  128 KB

  hipLaunchKernelGGL(ldt_kernel, dim3(256), dim3(256), 0, stream, ld, ldT);
  hipLaunchKernelGGL(wprep_kernel, dim3(N_OUT), dim3(256), 0, stream, wgt, lup, Wcat);
  hipLaunchKernelGGL(xprep_kernel, dim3(M_TOK / 16), dim3(256), 0, stream,
                     x, smooth, ldT, Xcat);
  hipLaunchKernelGGL(gemm_kernel, dim3((M_TOK / 256) * (N_OUT / 256)), dim3(512), 0, stream,
                     Xcat, Wcat, bias, out);
}

// Round 4
// 217.180 us; speedup vs baseline: 1.0083x; 1.0073x over previous
//
#include <hip/hip_runtime.h>
#include <stdint.h>

// SVDQuant forward on MI355X:
//   y = Q4(x*smooth) @ Q4(Wres)^T + (x*smooth) @ lora_down @ lora_up^T + bias
// R8 structure (3 kernels):
//   K1 wprep_kernel (grid 2080, NO LDS):
//      blocks [0,2048): Wcat[:,0:2048]=fakequant(Wres), [2048:2080)=bf16(lora_up),
//                       [2080:2112)=0.
//      blocks [2048,2080): ldT[32][2048] = bf16(lora_down^T) (row b-2048).
//   K2 xprep_kernel (grid 512): 16 x-rows each. Phase A: coalesced
//      fakequant(x*smooth) -> Xcat[:,0:2048] + bf16 x_s in LDS. Phase B:
//      rank-32 MFMA t = x_s @ lora_down -> Xcat[:,2048:2080]; pad = 0.
//   K3 gemm_kernel: out = Xcat @ Wcat^T + bias, K=2112 = 66x32.
//     256x256 tile, BK=32, 512 thr (8 waves 2Mx4N, wave-tile 128x64),
//     3-buffer LDS ring (96 KiB), 2 phases/K-tile. R8: phases PINNED so they
//     survive codegen (R5/R6/R7 all emitted ~the same schedule -> 906 TF):
//     each phase = {ds_read frags; issue 2 staging loads; sched_barrier(0);
//     s_barrier; asm lgkmcnt(0); sched_barrier(0) [rule #18]; setprio(1);
//     16 MFMA; setprio(0); sched_barrier(0); s_barrier}; one counted vmcnt(4)
//     per tile end (t+2's 4 loads stay in flight across barriers).
//     2-way-max chunk swizzle (pre-swizzled source + swizzled ds_read),
//     XCD-chunked blockIdx.

typedef __attribute__((ext_vector_type(8))) short short8;
typedef __attribute__((ext_vector_type(8))) unsigned short ushort8;
typedef __attribute__((ext_vector_type(4))) unsigned short ushort4v;
typedef __attribute__((ext_vector_type(4))) float floatx4;

#define M_TOK 8192
#define K_IN  2048
#define N_OUT 2048
#define RANK  32
#define KC    2112      // 2048 quant + 32 lowrank + 32 zero pad = 66 * 32
#define NTILE 66        // K-tiles of 32
#define XS_STRIDE 2056  // LDS x_s row stride (shorts): +8 -> 4-bank row rotation

// round-to-nearest-even f32 -> bf16 (finite inputs only)
__device__ __forceinline__ unsigned short f2bf(float f) {
  unsigned int u = __float_as_uint(f);
  u += 0x7fff + ((u >> 16) & 1);
  return (unsigned short)(u >> 16);
}

// fakequant 8 values held by this lane; group of 64 = 8 consecutive lanes
__device__ __forceinline__ void quant8(const float* v, unsigned short* q) {
  float amax = 0.f;
#pragma unroll
  for (int i = 0; i < 8; ++i) amax = fmaxf(amax, fabsf(v[i]));
  amax = fmaxf(amax, __shfl_xor(amax, 1, 64));
  amax = fmaxf(amax, __shfl_xor(amax, 2, 64));
  amax = fmaxf(amax, __shfl_xor(amax, 4, 64));
  float scale = fmaxf(amax / 7.0f, 1e-8f);
#pragma unroll
  for (int i = 0; i < 8; ++i) {
    float qq = rintf(v[i] / scale);   // IEEE div + RNE == jnp.round(g/scale)
    qq = fminf(fmaxf(qq, -7.f), 7.f);
    q[i] = f2bf(qq * scale);
  }
}

// ---------------- K1: W prep + lora_down transpose (no LDS) -----------------
__global__ __launch_bounds__(256) void wprep_kernel(const float* __restrict__ wgt,
                                                    const float* __restrict__ lup,
                                                    const float* __restrict__ ld,
                                                    unsigned short* __restrict__ Wcat,
                                                    unsigned short* __restrict__ ldT) {
  int tid = threadIdx.x;
  if (blockIdx.x >= 2048) {
    // ldT row r = bid-2048: ldT[r][k0..k0+8) = bf16(ld[k0..k0+8][r])
    int r = blockIdx.x - 2048, k0 = tid * 8;
    ushort8 o;
#pragma unroll
    for (int j = 0; j < 8; ++j) o[j] = f2bf(ld[(size_t)(k0 + j) * RANK + r]);
    *(ushort8*)(ldT + (size_t)r * 2048 + k0) = o;
    return;
  }
  int row = blockIdx.x;
  const float4* wr = (const float4*)(wgt + (size_t)row * K_IN);
  float4 a0 = wr[tid * 2], a1 = wr[tid * 2 + 1];
  float v[8] = {a0.x, a0.y, a0.z, a0.w, a1.x, a1.y, a1.z, a1.w};
  ushort8 q;
  quant8(v, (unsigned short*)&q);
  *(ushort8*)(Wcat + (size_t)row * KC + tid * 8) = q;
  if (tid < 32)      Wcat[(size_t)row * KC + 2048 + tid] = f2bf(lup[row * RANK + tid]);
  else if (tid < 64) Wcat[(size_t)row * KC + 2048 + tid] = 0;
}

// ---------------- K2: X prep ------------------------------------------------
__global__ __launch_bounds__(256) void xprep_kernel(const float* __restrict__ x,
                                                    const float* __restrict__ smooth,
                                                    const unsigned short* __restrict__ ldT,
                                                    unsigned short* __restrict__ Xcat) {
  __shared__ unsigned short xs[16 * XS_STRIDE];  // 64.25 KiB bf16 x_s
  __shared__ float red[4][16][32];               // 8 KiB
  int tid = threadIdx.x;
  int rowbase = blockIdx.x * 16;
  int w = tid >> 6, lane = tid & 63, quad = lane >> 4, l16 = lane & 15;

  // Phase A: coalesced quantize, one row per pass (256 thr x 8 elems = 2048)
  const float4* sr = (const float4*)smooth;
  float4 s0 = sr[tid * 2], s1 = sr[tid * 2 + 1];
#pragma unroll 4
  for (int r = 0; r < 16; ++r) {
    const float4* xr = (const float4*)(x + (size_t)(rowbase + r) * K_IN);
    float4 a0 = xr[tid * 2], a1 = xr[tid * 2 + 1];
    float v[8] = {a0.x * s0.x, a0.y * s0.y, a0.z * s0.z, a0.w * s0.w,
                  a1.x * s1.x, a1.y * s1.y, a1.z * s1.z, a1.w * s1.w};
    ushort8 q;
    quant8(v, (unsigned short*)&q);
    *(ushort8*)(Xcat + (size_t)(rowbase + r) * KC + tid * 8) = q;
    ushort8 sb;
#pragma unroll
    for (int t = 0; t < 8; ++t) sb[t] = f2bf(v[t]);
    *(ushort8*)(xs + r * XS_STRIDE + tid * 8) = sb;
  }
  // zero pad Xcat[:, 2080:2112): 16 threads x 4B per row
  *(unsigned int*)(Xcat + (size_t)(rowbase + (tid >> 4)) * KC + 2080 + (tid & 15) * 2) = 0u;
  __syncthreads();

  // Phase B: t = x_s @ lora_down. wave w covers k in [w*512, w*512+512).
  floatx4 acc[2];
  acc[0] = (floatx4)0.f;
  acc[1] = (floatx4)0.f;
  int kbase = w * 512;
#pragma unroll 2
  for (int it = 0; it < 16; ++it) {
    int k = kbase + it * 32 + quad * 8;
    short8 af = *(const short8*)(xs + l16 * XS_STRIDE + k);
    // B-frag: B[k=quad*8+j][n=l16 (+16)] = ldT[n][k..k+7] -- one 16B load each
    short8 b0 = *(const short8*)(ldT + (size_t)l16 * 2048 + k);
    short8 b1 = *(const short8*)(ldT + (size_t)(16 + l16) * 2048 + k);
    acc[0] = __builtin_amdgcn_mfma_f32_16x16x32_bf16(af, b0, acc[0], 0, 0, 0);
    acc[1] = __builtin_amdgcn_mfma_f32_16x16x32_bf16(af, b1, acc[1], 0, 0, 0);
  }
  // C layout: row = quad*4 + r, col = l16 (+16 for acc[1])
#pragma unroll
  for (int nt = 0; nt < 2; ++nt)
#pragma unroll
    for (int r = 0; r < 4; ++r)
      red[w][quad * 4 + r][nt * 16 + l16] = acc[nt][r];
  __syncthreads();
  if (tid < 128) {
    int rl = tid >> 3, seg = tid & 7;  // row 0..15, col segment of 4
    ushort4v o;
#pragma unroll
    for (int j = 0; j < 4; ++j) {
      int c = seg * 4 + j;
      float s = red[0][rl][c] + red[1][rl][c] + red[2][rl][c] + red[3][rl][c];
      o[j] = f2bf(s);
    }
    *(ushort4v*)(Xcat + (size_t)(rowbase + rl) * KC + 2048 + seg * 4) = o;
  }
}

// ---------------- K3: main GEMM: out = Xcat @ Wcat^T + bias ----------------
__device__ __forceinline__ void gld_lds16(const unsigned short* g, unsigned short* l) {
  __builtin_amdgcn_global_load_lds(
      (const __attribute__((address_space(1))) unsigned int*)g,
      (__attribute__((address_space(3))) unsigned int*)l, 16, 0, 0);
}

__global__ __launch_bounds__(512) void gemm_kernel(const unsigned short* __restrict__ Xcat,
                                                   const unsigned short* __restrict__ Wcat,
                                                   const float* __restrict__ bias,
                                                   float* __restrict__ out) {
  // ring of 3 K-tile buffers x (A 256x32 + B 256x32) bf16 = 96 KiB
  __shared__ unsigned short smem[49152];
  int tid = threadIdx.x;
  int w = tid >> 6, lane = tid & 63, quad = lane >> 4, l16 = lane & 15;
  int wm = w >> 2, wn = w & 3;  // 2 M-waves x 4 N-waves; wave tile 128x64

  // Bijective XCD chunking: grid 256 = 8 XCDs x 32; each XCD gets a contiguous
  // chunk = 4 M-panels x 8 N-panels -> A/B panel slabs stay L2-resident.
  int bid = blockIdx.x;
  int wg = (bid & 7) * 32 + (bid >> 3);
  int bM = (wg >> 3) * 256;
  int bN = (wg & 7) * 256;

  // Staging: per K-tile, A = 256 rows x 4 chunks(16B) = 16KB = 2 load rounds
  // (rows 0-127 / 128-255), same for B -> 4 loads per tile, 2 issued per phase.
  // thread covers (row = tid/4, chunk slot = tid&3); source chunk pre-swizzled
  // with (row>>1)&3 == (tid>>3)&3 so swizzled ds_reads see linear data.
  int srow = tid >> 2;                  // 0..127
  int csrc = (tid & 3) ^ ((tid >> 3) & 3);
  const unsigned short* Ag = Xcat + (size_t)(bM + srow) * KC + csrc * 8;
  const unsigned short* Bg = Wcat + (size_t)(bN + srow) * KC + csrc * 8;
  int ldsw = w * 512;                   // wave-uniform dest: lane*16B within

  // fragment LDS offsets (shorts): row*32 + swizzled chunk; (row>>1)&3 == (l16>>1)&3
  int ck = (quad ^ ((l16 >> 1) & 3)) * 8;
  int aoff[8], boff[4];
#pragma unroll
  for (int mt = 0; mt < 8; ++mt) aoff[mt] = (wm * 128 + mt * 16 + l16) * 32 + ck;
#pragma unroll
  for (int nt = 0; nt < 4; ++nt) boff[nt] = 8192 + (wn * 64 + nt * 16 + l16) * 32 + ck;

  floatx4 acc[8][4];
#pragma unroll
  for (int mt = 0; mt < 8; ++mt)
#pragma unroll
    for (int nt = 0; nt < 4; ++nt) acc[mt][nt] = (floatx4)0.f;

  int b0 = 0, b1 = 16384, b2 = 32768;   // ring: read b0, next b1, stage into b2

#define STAGE_A(tt, OFF)                                                      \
  do {                                                                        \
    int k0_ = (tt) * 32;                                                      \
    gld_lds16(Ag + k0_,            smem + (OFF) + ldsw);                      \
    gld_lds16(Ag + 128 * KC + k0_, smem + (OFF) + 4096 + ldsw);               \
  } while (0)
#define STAGE_B(tt, OFF)                                                      \
  do {                                                                        \
    int k0_ = (tt) * 32;                                                      \
    gld_lds16(Bg + k0_,            smem + (OFF) + 8192 + ldsw);               \
    gld_lds16(Bg + 128 * KC + k0_, smem + (OFF) + 12288 + ldsw);              \
  } while (0)

  // prologue: tiles 0,1 fully staged; certify tile 0 (4 newest stay in flight)
  STAGE_A(0, 0);
  STAGE_B(0, 0);
  STAGE_A(1, 16384);
  STAGE_B(1, 16384);
  asm volatile("s_waitcnt vmcnt(4)" ::: "memory");
  __builtin_amdgcn_s_barrier();

#pragma unroll 1
  for (int t = 0; t < NTILE; ++t) {
    unsigned short* sb = smem + b0;
    short8 a[4], b[4];

    // ---- phase 0: mt 0-3 x nt 0-3; interleave A-staging of tile t+2 ----
#pragma unroll
    for (int mt = 0; mt < 4; ++mt) a[mt] = *(const short8*)(sb + aoff[mt]);
#pragma unroll
    for (int nt = 0; nt < 4; ++nt) b[nt] = *(const short8*)(sb + boff[nt]);
    if (t + 2 < NTILE) STAGE_A(t + 2, b2);
    __builtin_amdgcn_sched_barrier(0);          // pin: reads stay before barrier
    __builtin_amdgcn_s_barrier();
    asm volatile("s_waitcnt lgkmcnt(0)" ::: "memory");
    __builtin_amdgcn_sched_barrier(0);          // rule #18: MFMA must not hoist
    __builtin_amdgcn_s_setprio(1);
#pragma unroll
    for (int mt = 0; mt < 4; ++mt)
#pragma unroll
      for (int nt = 0; nt < 4; ++nt)
        acc[mt][nt] = __builtin_amdgcn_mfma_f32_16x16x32_bf16(a[mt], b[nt], acc[mt][nt], 0, 0, 0);
    __builtin_amdgcn_s_setprio(0);
    __builtin_amdgcn_sched_barrier(0);          // pin: MFMA cluster stays here
    __builtin_amdgcn_s_barrier();

    // ---- phase 1: mt 4-7 x nt 0-3 (reuse b); interleave B-staging ----
#pragma unroll
    for (int mt = 0; mt < 4; ++mt) a[mt] = *(const short8*)(sb + aoff[mt + 4]);
    if (t + 2 < NTILE) STAGE_B(t + 2, b2);
    __builtin_amdgcn_sched_barrier(0);
    __builtin_amdgcn_s_barrier();
    asm volatile("s_waitcnt lgkmcnt(0)" ::: "memory");
    __builtin_amdgcn_sched_barrier(0);
    __builtin_amdgcn_s_setprio(1);
#pragma unroll
    for (int mt = 0; mt < 4; ++mt)
#pragma unroll
      for (int nt = 0; nt < 4; ++nt)
        acc[mt + 4][nt] = __builtin_amdgcn_mfma_f32_16x16x32_bf16(a[mt], b[nt], acc[mt + 4][nt], 0, 0, 0);
    __builtin_amdgcn_s_setprio(0);
    __builtin_amdgcn_sched_barrier(0);

    // ---- tile end: certify tile t+1 landed; t+2's 4 stay in flight ----
    if (t < NTILE - 2)
      asm volatile("s_waitcnt vmcnt(4)" ::: "memory");
    else if (t == NTILE - 2)
      asm volatile("s_waitcnt vmcnt(0)" ::: "memory");
    __builtin_amdgcn_s_barrier();
    int tmp = b0; b0 = b1; b1 = b2; b2 = tmp;
  }
#undef STAGE_A
#undef STAGE_B

  // epilogue: + bias, store fp32
#pragma unroll
  for (int nt = 0; nt < 4; ++nt) {
    int col = bN + wn * 64 + nt * 16 + l16;
    float bv = bias[col];
#pragma unroll
    for (int mt = 0; mt < 8; ++mt) {
      int row = bM + wm * 128 + mt * 16 + quad * 4;
#pragma unroll
      for (int r2 = 0; r2 < 4; ++r2)
        out[(size_t)(row + r2) * N_OUT + col] = acc[mt][nt][r2] + bv;
    }
  }
}

extern "C" void kernel_launch(void* const* d_in, const int* in_sizes, int n_in,
                              void* d_out, int out_size, void* d_ws, size_t ws_size,
                              hipStream_t stream) {
  const float* x      = (const float*)d_in[0];
  const float* wgt    = (const float*)d_in[1];
  const float* ld     = (const float*)d_in[2];
  const float* lup    = (const float*)d_in[3];
  const float* smooth = (const float*)d_in[4];
  const float* bias   = (const float*)d_in[5];
  float* out = (float*)d_out;

  unsigned short* Xcat = (unsigned short*)d_ws;                 // 8192*2112*2 = 34.6 MB
  unsigned short* Wcat = Xcat + (size_t)M_TOK * KC;             //  8.65 MB
  unsigned short* ldT  = Wcat + (size_t)N_OUT * KC;             //  128 KB

  hipLaunchKernelGGL(wprep_kernel, dim3(N_OUT + 32), dim3(256), 0, stream,
                     wgt, lup, ld, Wcat, ldT);
  hipLaunchKernelGGL(xprep_kernel, dim3(M_TOK / 16), dim3(256), 0, stream,
                     x, smooth, ldT, Xcat);
  hipLaunchKernelGGL(gemm_kernel, dim3((M_TOK / 256) * (N_OUT / 256)), dim3(512), 0, stream,
                     Xcat, Wcat, bias, out);
}

// Round 5
// 209.420 us; speedup vs baseline: 1.0456x; 1.0371x over previous
//
#include <hip/hip_runtime.h>
#include <stdint.h>

// SVDQuant forward on MI355X:
//   y = Q4(x*smooth) @ Q4(Wres)^T + (x*smooth) @ lora_down @ lora_up^T + bias
// R9 structure (3 kernels):
//   K1 wprep_kernel (grid 2080, NO LDS):
//      blocks [0,2048): Wcat[:,0:2048]=fakequant(Wres), [2048:2080)=bf16(lora_up),
//                       [2080:2112)=0.
//      blocks [2048,2080): ldT[32][2048] = bf16(lora_down^T) (row b-2048).
//   K2 xprep_kernel (grid 512): 16 x-rows each. Phase A: coalesced
//      fakequant(x*smooth) -> Xcat[:,0:2048] + bf16 x_s in LDS. Phase B:
//      rank-32 MFMA t = x_s @ lora_down -> Xcat[:,2048:2080]; pad = 0.
//   K3 gemm_kernel: out = Xcat @ Wcat^T + bias, K=2112 = 33x64.
//     R9: MINIMUM-BARRIER lifecycle. 256x256 tile, BK=64, 512 thr (8 waves
//     2Mx4N, wave-tile 128x64), 2x64KB LDS dbuf. Per tile: issue all 8
//     global_load_lds for tile t+1 at tile START (whole tile ~2400cy to land),
//     free-running compute (no mid-tile barriers -> wave skew overlaps ds_read
//     service with other waves' MFMA), then ONE vmcnt(0)+s_barrier per tile
//     (drain is cheap: loads issued ~2400cy earlier). 1 barrier/K64 vs R8's ~8.
//     2-way-max chunk swizzle (pre-swizzled source + swizzled ds_read),
//     XCD-chunked blockIdx.

typedef __attribute__((ext_vector_type(8))) short short8;
typedef __attribute__((ext_vector_type(8))) unsigned short ushort8;
typedef __attribute__((ext_vector_type(4))) unsigned short ushort4v;
typedef __attribute__((ext_vector_type(4))) float floatx4;

#define M_TOK 8192
#define K_IN  2048
#define N_OUT 2048
#define RANK  32
#define KC    2112      // 2048 quant + 32 lowrank + 32 zero pad = 33 * 64
#define NTILE 33        // K-tiles of 64
#define XS_STRIDE 2056  // LDS x_s row stride (shorts): +8 -> 4-bank row rotation

// round-to-nearest-even f32 -> bf16 (finite inputs only)
__device__ __forceinline__ unsigned short f2bf(float f) {
  unsigned int u = __float_as_uint(f);
  u += 0x7fff + ((u >> 16) & 1);
  return (unsigned short)(u >> 16);
}

// fakequant 8 values held by this lane; group of 64 = 8 consecutive lanes
__device__ __forceinline__ void quant8(const float* v, unsigned short* q) {
  float amax = 0.f;
#pragma unroll
  for (int i = 0; i < 8; ++i) amax = fmaxf(amax, fabsf(v[i]));
  amax = fmaxf(amax, __shfl_xor(amax, 1, 64));
  amax = fmaxf(amax, __shfl_xor(amax, 2, 64));
  amax = fmaxf(amax, __shfl_xor(amax, 4, 64));
  float scale = fmaxf(amax / 7.0f, 1e-8f);
#pragma unroll
  for (int i = 0; i < 8; ++i) {
    float qq = rintf(v[i] / scale);   // IEEE div + RNE == jnp.round(g/scale)
    qq = fminf(fmaxf(qq, -7.f), 7.f);
    q[i] = f2bf(qq * scale);
  }
}

// ---------------- K1: W prep + lora_down transpose (no LDS) -----------------
__global__ __launch_bounds__(256) void wprep_kernel(const float* __restrict__ wgt,
                                                    const float* __restrict__ lup,
                                                    const float* __restrict__ ld,
                                                    unsigned short* __restrict__ Wcat,
                                                    unsigned short* __restrict__ ldT) {
  int tid = threadIdx.x;
  if (blockIdx.x >= 2048) {
    // ldT row r = bid-2048: ldT[r][k0..k0+8) = bf16(ld[k0..k0+8][r])
    int r = blockIdx.x - 2048, k0 = tid * 8;
    ushort8 o;
#pragma unroll
    for (int j = 0; j < 8; ++j) o[j] = f2bf(ld[(size_t)(k0 + j) * RANK + r]);
    *(ushort8*)(ldT + (size_t)r * 2048 + k0) = o;
    return;
  }
  int row = blockIdx.x;
  const float4* wr = (const float4*)(wgt + (size_t)row * K_IN);
  float4 a0 = wr[tid * 2], a1 = wr[tid * 2 + 1];
  float v[8] = {a0.x, a0.y, a0.z, a0.w, a1.x, a1.y, a1.z, a1.w};
  ushort8 q;
  quant8(v, (unsigned short*)&q);
  *(ushort8*)(Wcat + (size_t)row * KC + tid * 8) = q;
  if (tid < 32)      Wcat[(size_t)row * KC + 2048 + tid] = f2bf(lup[row * RANK + tid]);
  else if (tid < 64) Wcat[(size_t)row * KC + 2048 + tid] = 0;
}

// ---------------- K2: X prep ------------------------------------------------
__global__ __launch_bounds__(256) void xprep_kernel(const float* __restrict__ x,
                                                    const float* __restrict__ smooth,
                                                    const unsigned short* __restrict__ ldT,
                                                    unsigned short* __restrict__ Xcat) {
  __shared__ unsigned short xs[16 * XS_STRIDE];  // 64.25 KiB bf16 x_s
  __shared__ float red[4][16][32];               // 8 KiB
  int tid = threadIdx.x;
  int rowbase = blockIdx.x * 16;
  int w = tid >> 6, lane = tid & 63, quad = lane >> 4, l16 = lane & 15;

  // Phase A: coalesced quantize, one row per pass (256 thr x 8 elems = 2048)
  const float4* sr = (const float4*)smooth;
  float4 s0 = sr[tid * 2], s1 = sr[tid * 2 + 1];
#pragma unroll 4
  for (int r = 0; r < 16; ++r) {
    const float4* xr = (const float4*)(x + (size_t)(rowbase + r) * K_IN);
    float4 a0 = xr[tid * 2], a1 = xr[tid * 2 + 1];
    float v[8] = {a0.x * s0.x, a0.y * s0.y, a0.z * s0.z, a0.w * s0.w,
                  a1.x * s1.x, a1.y * s1.y, a1.z * s1.z, a1.w * s1.w};
    ushort8 q;
    quant8(v, (unsigned short*)&q);
    *(ushort8*)(Xcat + (size_t)(rowbase + r) * KC + tid * 8) = q;
    ushort8 sb;
#pragma unroll
    for (int t = 0; t < 8; ++t) sb[t] = f2bf(v[t]);
    *(ushort8*)(xs + r * XS_STRIDE + tid * 8) = sb;
  }
  // zero pad Xcat[:, 2080:2112): 16 threads x 4B per row
  *(unsigned int*)(Xcat + (size_t)(rowbase + (tid >> 4)) * KC + 2080 + (tid & 15) * 2) = 0u;
  __syncthreads();

  // Phase B: t = x_s @ lora_down. wave w covers k in [w*512, w*512+512).
  floatx4 acc[2];
  acc[0] = (floatx4)0.f;
  acc[1] = (floatx4)0.f;
  int kbase = w * 512;
#pragma unroll 2
  for (int it = 0; it < 16; ++it) {
    int k = kbase + it * 32 + quad * 8;
    short8 af = *(const short8*)(xs + l16 * XS_STRIDE + k);
    // B-frag: B[k=quad*8+j][n=l16 (+16)] = ldT[n][k..k+7] -- one 16B load each
    short8 b0 = *(const short8*)(ldT + (size_t)l16 * 2048 + k);
    short8 b1 = *(const short8*)(ldT + (size_t)(16 + l16) * 2048 + k);
    acc[0] = __builtin_amdgcn_mfma_f32_16x16x32_bf16(af, b0, acc[0], 0, 0, 0);
    acc[1] = __builtin_amdgcn_mfma_f32_16x16x32_bf16(af, b1, acc[1], 0, 0, 0);
  }
  // C layout: row = quad*4 + r, col = l16 (+16 for acc[1])
#pragma unroll
  for (int nt = 0; nt < 2; ++nt)
#pragma unroll
    for (int r = 0; r < 4; ++r)
      red[w][quad * 4 + r][nt * 16 + l16] = acc[nt][r];
  __syncthreads();
  if (tid < 128) {
    int rl = tid >> 3, seg = tid & 7;  // row 0..15, col segment of 4
    ushort4v o;
#pragma unroll
    for (int j = 0; j < 4; ++j) {
      int c = seg * 4 + j;
      float s = red[0][rl][c] + red[1][rl][c] + red[2][rl][c] + red[3][rl][c];
      o[j] = f2bf(s);
    }
    *(ushort4v*)(Xcat + (size_t)(rowbase + rl) * KC + 2048 + seg * 4) = o;
  }
}

// ---------------- K3: main GEMM: out = Xcat @ Wcat^T + bias ----------------
__device__ __forceinline__ void gld_lds16(const unsigned short* g, unsigned short* l) {
  __builtin_amdgcn_global_load_lds(
      (const __attribute__((address_space(1))) unsigned int*)g,
      (__attribute__((address_space(3))) unsigned int*)l, 16, 0, 0);
}

__global__ __launch_bounds__(512) void gemm_kernel(const unsigned short* __restrict__ Xcat,
                                                   const unsigned short* __restrict__ Wcat,
                                                   const float* __restrict__ bias,
                                                   float* __restrict__ out) {
  // 2 K-tile buffers x (A 256x64 + B 256x64) bf16 = 128 KiB, 1 block/CU
  __shared__ unsigned short smem[65536];
  int tid = threadIdx.x;
  int w = tid >> 6, lane = tid & 63, quad = lane >> 4, l16 = lane & 15;
  int wm = w >> 2, wn = w & 3;  // 2 M-waves x 4 N-waves; wave tile 128x64

  // Bijective XCD chunking: grid 256 = 8 XCDs x 32; each XCD gets a contiguous
  // chunk = 4 M-panels x 8 N-panels -> A/B panel slabs stay L2-resident.
  int bid = blockIdx.x;
  int wg = (bid & 7) * 32 + (bid >> 3);
  int bM = (wg >> 3) * 256;
  int bN = (wg & 7) * 256;

  // Staging: per K-tile, A = 256 rows x 8 chunks(16B) = 32KB (same B), 4 slices
  // of 64 rows each. thread covers (row = 64*i + tid/8, chunk slot = tid&7);
  // source chunk pre-swizzled with row&7 == (tid>>3)&7 so swizzled reads match.
  int srow = tid >> 3;                  // 0..63
  int csrc = (tid & 7) ^ (srow & 7);
  const unsigned short* Ag = Xcat + (size_t)(bM + srow) * KC + csrc * 8;
  const unsigned short* Bg = Wcat + (size_t)(bN + srow) * KC + csrc * 8;
  int ldsrow = w * 512;                 // wave-uniform dest: w*8 rows * 64 shorts

#define STAGE(tt, OFF)                                                        \
  do {                                                                        \
    int k0_ = (tt) * 64;                                                      \
    gld_lds16(Ag + k0_,            smem + (OFF) + ldsrow);                    \
    gld_lds16(Ag + 64 * KC + k0_,  smem + (OFF) + 4096 + ldsrow);             \
    gld_lds16(Ag + 128 * KC + k0_, smem + (OFF) + 8192 + ldsrow);             \
    gld_lds16(Ag + 192 * KC + k0_, smem + (OFF) + 12288 + ldsrow);            \
    gld_lds16(Bg + k0_,            smem + (OFF) + 16384 + ldsrow);            \
    gld_lds16(Bg + 64 * KC + k0_,  smem + (OFF) + 20480 + ldsrow);            \
    gld_lds16(Bg + 128 * KC + k0_, smem + (OFF) + 24576 + ldsrow);            \
    gld_lds16(Bg + 192 * KC + k0_, smem + (OFF) + 28672 + ldsrow);            \
  } while (0)

  // fragment LDS offsets (shorts): row*64 + swizzled chunk; row&7 == l16&7.
  int l7 = l16 & 7;
  int ck0 = (quad ^ l7) * 8;            // kk = 0 chunk (global chunks 0-3)
  int ck1 = ((4 + quad) ^ l7) * 8;      // kk = 1 chunk (global chunks 4-7)
  int aoff[8], boff[4];
#pragma unroll
  for (int mt = 0; mt < 8; ++mt) aoff[mt] = (wm * 128 + mt * 16 + l16) * 64;
#pragma unroll
  for (int nt = 0; nt < 4; ++nt) boff[nt] = 16384 + (wn * 64 + nt * 16 + l16) * 64;

  floatx4 acc[8][4];
#pragma unroll
  for (int mt = 0; mt < 8; ++mt)
#pragma unroll
    for (int nt = 0; nt < 4; ++nt) acc[mt][nt] = (floatx4)0.f;

  // prologue: stage tile 0, certify, go
  STAGE(0, 0);
  asm volatile("s_waitcnt vmcnt(0)" ::: "memory");
  __builtin_amdgcn_s_barrier();

#pragma unroll 1
  for (int t = 0; t < NTILE; ++t) {
    unsigned short* sb = smem + (t & 1) * 32768;

    // issue ALL of tile t+1's staging first: ~full tile of latency cover,
    // target buffer was freed by the previous tile-end barrier.
    if (t + 1 < NTILE) STAGE(t + 1, ((t + 1) & 1) * 32768);

    short8 a[8], b[4];
    // ---- kk0: 32 MFMA ----
#pragma unroll
    for (int mt = 0; mt < 8; ++mt) a[mt] = *(const short8*)(sb + aoff[mt] + ck0);
#pragma unroll
    for (int nt = 0; nt < 4; ++nt) b[nt] = *(const short8*)(sb + boff[nt] + ck0);
    __builtin_amdgcn_s_setprio(1);
#pragma unroll
    for (int mt = 0; mt < 8; ++mt)
#pragma unroll
      for (int nt = 0; nt < 4; ++nt)
        acc[mt][nt] = __builtin_amdgcn_mfma_f32_16x16x32_bf16(a[mt], b[nt], acc[mt][nt], 0, 0, 0);
    __builtin_amdgcn_s_setprio(0);

    // ---- kk1: 32 MFMA ----
#pragma unroll
    for (int mt = 0; mt < 8; ++mt) a[mt] = *(const short8*)(sb + aoff[mt] + ck1);
#pragma unroll
    for (int nt = 0; nt < 4; ++nt) b[nt] = *(const short8*)(sb + boff[nt] + ck1);
    __builtin_amdgcn_s_setprio(1);
#pragma unroll
    for (int mt = 0; mt < 8; ++mt)
#pragma unroll
      for (int nt = 0; nt < 4; ++nt)
        acc[mt][nt] = __builtin_amdgcn_mfma_f32_16x16x32_bf16(a[mt], b[nt], acc[mt][nt], 0, 0, 0);
    __builtin_amdgcn_s_setprio(0);

    // ---- single tile-end certification: everyone's reads of sb are done
    // (register data), and every wave's 8 staging loads for t+1 have landed
    // (issued a whole tile ago -> drain is cheap). One barrier per K=64.
    if (t + 1 < NTILE) {
      asm volatile("s_waitcnt vmcnt(0)" ::: "memory");
      __builtin_amdgcn_s_barrier();
    }
  }
#undef STAGE

  // epilogue: + bias, store fp32
#pragma unroll
  for (int nt = 0; nt < 4; ++nt) {
    int col = bN + wn * 64 + nt * 16 + l16;
    float bv = bias[col];
#pragma unroll
    for (int mt = 0; mt < 8; ++mt) {
      int row = bM + wm * 128 + mt * 16 + quad * 4;
#pragma unroll
      for (int r2 = 0; r2 < 4; ++r2)
        out[(size_t)(row + r2) * N_OUT + col] = acc[mt][nt][r2] + bv;
    }
  }
}

extern "C" void kernel_launch(void* const* d_in, const int* in_sizes, int n_in,
                              void* d_out, int out_size, void* d_ws, size_t ws_size,
                              hipStream_t stream) {
  const float* x      = (const float*)d_in[0];
  const float* wgt    = (const float*)d_in[1];
  const float* ld     = (const float*)d_in[2];
  const float* lup    = (const float*)d_in[3];
  const float* smooth = (const float*)d_in[4];
  const float* bias   = (const float*)d_in[5];
  float* out = (float*)d_out;

  unsigned short* Xcat = (unsigned short*)d_ws;                 // 8192*2112*2 = 34.6 MB
  unsigned short* Wcat = Xcat + (size_t)M_TOK * KC;             //  8.65 MB
  unsigned short* ldT  = Wcat + (size_t)N_OUT * KC;             //  128 KB

  hipLaunchKernelGGL(wprep_kernel, dim3(N_OUT + 32), dim3(256), 0, stream,
                     wgt, lup, ld, Wcat, ldT);
  hipLaunchKernelGGL(xprep_kernel, dim3(M_TOK / 16), dim3(256), 0, stream,
                     x, smooth, ldT, Xcat);
  hipLaunchKernelGGL(gemm_kernel, dim3((M_TOK / 256) * (N_OUT / 256)), dim3(512), 0, stream,
                     Xcat, Wcat, bias, out);
}

// Round 7
// 206.460 us; speedup vs baseline: 1.0606x; 1.0143x over previous
//
#include <hip/hip_runtime.h>
#include <stdint.h>

// SVDQuant forward on MI355X:
//   y = Q4(x*smooth) @ Q4(Wres)^T + (x*smooth) @ lora_down @ lora_up^T + bias
// R10 structure (2 kernels — dispatch overhead ~8-10us each, so merge preps):
//   K1 prep_kernel (grid 2560, R0-proven merged form):
//     blocks [0,512):   16 x-rows each. Phase A: coalesced fakequant(x*smooth)
//                       -> Xcat[:,0:2048] + bf16 x_s in LDS. Phase B: rank-32
//                       MFMA t = x_s @ lora_down (B-frag from ld directly)
//                       -> Xcat[:,2048:2080]; pad [2080:2112)=0.
//     blocks [512,2560): 1 w-row each: Wcat[:,0:2048]=fakequant(Wres),
//                       [2048:2080)=bf16(lora_up), [2080:2112)=0.
//   K2 gemm_kernel: out = Xcat @ Wcat^T + bias, K=2112 = 33x64.
//     R10: R9's minimum-barrier lifecycle (BK=64, 2x64KB dbuf, stage tile t+1
//     at tile start, ONE vmcnt(0)+s_barrier per tile) + INTRA-TILE ILP:
//     fragment reads for MFMA-cluster g+1 are issued BEFORE cluster g's MFMA
//     burst, so ds_read service hides under the matrix pipe instead of
//     serializing read-burst -> MFMA-burst (R9 counters: MfmaUtil 40 + VALU 17
//     -> 44% idle = alternation). 2-way-max chunk swizzle, XCD-chunked blockIdx.

typedef __attribute__((ext_vector_type(8))) short short8;
typedef __attribute__((ext_vector_type(8))) unsigned short ushort8;
typedef __attribute__((ext_vector_type(4))) unsigned short ushort4v;
typedef __attribute__((ext_vector_type(4))) float floatx4;

#define M_TOK 8192
#define K_IN  2048
#define N_OUT 2048
#define RANK  32
#define KC    2112      // 2048 quant + 32 lowrank + 32 zero pad = 33 * 64
#define NTILE 33        // K-tiles of 64
#define XS_STRIDE 2056  // LDS x_s row stride (shorts): +8 -> 4-bank row rotation

// round-to-nearest-even f32 -> bf16 (finite inputs only)
__device__ __forceinline__ unsigned short f2bf(float f) {
  unsigned int u = __float_as_uint(f);
  u += 0x7fff + ((u >> 16) & 1);
  return (unsigned short)(u >> 16);
}

// fakequant 8 values held by this lane; group of 64 = 8 consecutive lanes
__device__ __forceinline__ void quant8(const float* v, unsigned short* q) {
  float amax = 0.f;
#pragma unroll
  for (int i = 0; i < 8; ++i) amax = fmaxf(amax, fabsf(v[i]));
  amax = fmaxf(amax, __shfl_xor(amax, 1, 64));
  amax = fmaxf(amax, __shfl_xor(amax, 2, 64));
  amax = fmaxf(amax, __shfl_xor(amax, 4, 64));
  float scale = fmaxf(amax / 7.0f, 1e-8f);
#pragma unroll
  for (int i = 0; i < 8; ++i) {
    float qq = rintf(v[i] / scale);   // IEEE div + RNE == jnp.round(g/scale)
    qq = fminf(fmaxf(qq, -7.f), 7.f);
    q[i] = f2bf(qq * scale);
  }
}

// ---------------- K1: fused prep (R0-proven) --------------------------------
__global__ __launch_bounds__(256) void prep_kernel(const float* __restrict__ x,
                                                   const float* __restrict__ smooth,
                                                   const float* __restrict__ wgt,
                                                   const float* __restrict__ ld,
                                                   const float* __restrict__ lup,
                                                   unsigned short* __restrict__ Xcat,
                                                   unsigned short* __restrict__ Wcat) {
  __shared__ unsigned short xs[16 * XS_STRIDE];  // 64.25 KiB bf16 x_s
  __shared__ float red[4][16][32];               // 8 KiB
  int tid = threadIdx.x;

  if (blockIdx.x >= 512) {
    // ---- W path: one row of Wres per block ----
    int row = blockIdx.x - 512;
    const float4* wr = (const float4*)(wgt + (size_t)row * K_IN);
    float4 a0 = wr[tid * 2], a1 = wr[tid * 2 + 1];
    float v[8] = {a0.x, a0.y, a0.z, a0.w, a1.x, a1.y, a1.z, a1.w};
    ushort8 q;
    quant8(v, (unsigned short*)&q);
    *(ushort8*)(Wcat + (size_t)row * KC + tid * 8) = q;
    if (tid < 32)      Wcat[(size_t)row * KC + 2048 + tid] = f2bf(lup[row * RANK + tid]);
    else if (tid < 64) Wcat[(size_t)row * KC + 2048 + tid] = 0;
    return;
  }

  // ---- X path: 16 rows per block ----
  int rowbase = blockIdx.x * 16;
  int w = tid >> 6, lane = tid & 63, quad = lane >> 4, l16 = lane & 15;

  // Phase A: coalesced quantize, one row per pass (256 thr x 8 elems = 2048)
  const float4* sr = (const float4*)smooth;
  float4 s0 = sr[tid * 2], s1 = sr[tid * 2 + 1];
#pragma unroll 2
  for (int r = 0; r < 16; ++r) {
    const float4* xr = (const float4*)(x + (size_t)(rowbase + r) * K_IN);
    float4 a0 = xr[tid * 2], a1 = xr[tid * 2 + 1];
    float v[8] = {a0.x * s0.x, a0.y * s0.y, a0.z * s0.z, a0.w * s0.w,
                  a1.x * s1.x, a1.y * s1.y, a1.z * s1.z, a1.w * s1.w};
    ushort8 q;
    quant8(v, (unsigned short*)&q);
    *(ushort8*)(Xcat + (size_t)(rowbase + r) * KC + tid * 8) = q;
    ushort8 sb;
#pragma unroll
    for (int t = 0; t < 8; ++t) sb[t] = f2bf(v[t]);
    *(ushort8*)(xs + r * XS_STRIDE + tid * 8) = sb;
  }
  // zero pad Xcat[:, 2080:2112): 16 threads x 4B per row
  *(unsigned int*)(Xcat + (size_t)(rowbase + (tid >> 4)) * KC + 2080 + (tid & 15) * 2) = 0u;
  __syncthreads();

  // Phase B: t = x_s @ lora_down. wave w covers k in [w*512, w*512+512).
  floatx4 acc[2];
  acc[0] = (floatx4)0.f;
  acc[1] = (floatx4)0.f;
  int kbase = w * 512;
#pragma unroll 2
  for (int it = 0; it < 16; ++it) {
    int k = kbase + it * 32 + quad * 8;
    short8 af = *(const short8*)(xs + l16 * XS_STRIDE + k);
    // B-frag straight from lora_down [k][r]: B[k=quad*8+j][n=l16 (+16)]
    short8 b0, b1;
#pragma unroll
    for (int j = 0; j < 8; ++j) {
      b0[j] = (short)f2bf(ld[(size_t)(k + j) * RANK + l16]);
      b1[j] = (short)f2bf(ld[(size_t)(k + j) * RANK + 16 + l16]);
    }
    acc[0] = __builtin_amdgcn_mfma_f32_16x16x32_bf16(af, b0, acc[0], 0, 0, 0);
    acc[1] = __builtin_amdgcn_mfma_f32_16x16x32_bf16(af, b1, acc[1], 0, 0, 0);
  }
  // C layout: row = quad*4 + r, col = l16 (+16 for acc[1])
#pragma unroll
  for (int nt = 0; nt < 2; ++nt)
#pragma unroll
    for (int r = 0; r < 4; ++r)
      red[w][quad * 4 + r][nt * 16 + l16] = acc[nt][r];
  __syncthreads();
  if (tid < 128) {
    int rl = tid >> 3, seg = tid & 7;  // row 0..15, col segment of 4
    ushort4v o;
#pragma unroll
    for (int j = 0; j < 4; ++j) {
      int c = seg * 4 + j;
      float s = red[0][rl][c] + red[1][rl][c] + red[2][rl][c] + red[3][rl][c];
      o[j] = f2bf(s);
    }
    *(ushort4v*)(Xcat + (size_t)(rowbase + rl) * KC + 2048 + seg * 4) = o;
  }
}

// ---------------- K2: main GEMM: out = Xcat @ Wcat^T + bias ----------------
__device__ __forceinline__ void gld_lds16(const unsigned short* g, unsigned short* l) {
  __builtin_amdgcn_global_load_lds(
      (const __attribute__((address_space(1))) unsigned int*)g,
      (__attribute__((address_space(3))) unsigned int*)l, 16, 0, 0);
}

__global__ __launch_bounds__(512) void gemm_kernel(const unsigned short* __restrict__ Xcat,
                                                   const unsigned short* __restrict__ Wcat,
                                                   const float* __restrict__ bias,
                                                   float* __restrict__ out) {
  // 2 K-tile buffers x (A 256x64 + B 256x64) bf16 = 128 KiB, 1 block/CU
  __shared__ unsigned short smem[65536];
  int tid = threadIdx.x;
  int w = tid >> 6, lane = tid & 63, quad = lane >> 4, l16 = lane & 15;
  int wm = w >> 2, wn = w & 3;  // 2 M-waves x 4 N-waves; wave tile 128x64

  // Bijective XCD chunking: grid 256 = 8 XCDs x 32; each XCD gets a contiguous
  // chunk = 4 M-panels x 8 N-panels -> A/B panel slabs stay L2-resident.
  int bid = blockIdx.x;
  int wg = (bid & 7) * 32 + (bid >> 3);
  int bM = (wg >> 3) * 256;
  int bN = (wg & 7) * 256;

  // Staging: per K-tile, A = 256 rows x 8 chunks(16B) = 32KB (same B), 4 slices
  // of 64 rows each. thread covers (row = 64*i + tid/8, chunk slot = tid&7);
  // source chunk pre-swizzled with row&7 == (tid>>3)&7 so swizzled reads match.
  int srow = tid >> 3;                  // 0..63
  int csrc = (tid & 7) ^ (srow & 7);
  const unsigned short* Ag = Xcat + (size_t)(bM + srow) * KC + csrc * 8;
  const unsigned short* Bg = Wcat + (size_t)(bN + srow) * KC + csrc * 8;
  int ldsrow = w * 512;                 // wave-uniform dest: w*8 rows * 64 shorts

#define STAGE(tt, OFF)                                                        \
  do {                                                                        \
    int k0_ = (tt) * 64;                                                      \
    gld_lds16(Ag + k0_,            smem + (OFF) + ldsrow);                    \
    gld_lds16(Ag + 64 * KC + k0_,  smem + (OFF) + 4096 + ldsrow);             \
    gld_lds16(Ag + 128 * KC + k0_, smem + (OFF) + 8192 + ldsrow);             \
    gld_lds16(Ag + 192 * KC + k0_, smem + (OFF) + 12288 + ldsrow);            \
    gld_lds16(Bg + k0_,            smem + (OFF) + 16384 + ldsrow);            \
    gld_lds16(Bg + 64 * KC + k0_,  smem + (OFF) + 20480 + ldsrow);            \
    gld_lds16(Bg + 128 * KC + k0_, smem + (OFF) + 24576 + ldsrow);            \
    gld_lds16(Bg + 192 * KC + k0_, smem + (OFF) + 28672 + ldsrow);            \
  } while (0)

  // fragment LDS offsets (shorts): row*64 + swizzled chunk; row&7 == l16&7.
  int l7 = l16 & 7;
  int ck0 = (quad ^ l7) * 8;            // kk = 0 chunk (global chunks 0-3)
  int ck1 = ((4 + quad) ^ l7) * 8;      // kk = 1 chunk (global chunks 4-7)
  int aoff[8], boff[4];
#pragma unroll
  for (int mt = 0; mt < 8; ++mt) aoff[mt] = (wm * 128 + mt * 16 + l16) * 64;
#pragma unroll
  for (int nt = 0; nt < 4; ++nt) boff[nt] = 16384 + (wn * 64 + nt * 16 + l16) * 64;

  floatx4 acc[8][4];
#pragma unroll
  for (int mt = 0; mt < 8; ++mt)
#pragma unroll
    for (int nt = 0; nt < 4; ++nt) acc[mt][nt] = (floatx4)0.f;

  // prologue: stage tile 0, certify, go
  STAGE(0, 0);
  asm volatile("s_waitcnt vmcnt(0)" ::: "memory");
  __builtin_amdgcn_s_barrier();

#pragma unroll 1
  for (int t = 0; t < NTILE; ++t) {
    unsigned short* sb = smem + (t & 1) * 32768;

    // issue tile t+1's staging first: full tile of latency cover; target
    // buffer was freed by the previous tile-end barrier.
    if (t + 1 < NTILE) STAGE(t + 1, ((t + 1) & 1) * 32768);

    short8 b0[4], b1[4], a00[4], a01[4], a10[4], a11[4];

    // ---- pipelined clusters: reads for cluster g+1 issue BEFORE cluster g's
    // MFMA burst, so ds_read service hides under the matrix pipe. ----
#pragma unroll
    for (int nt = 0; nt < 4; ++nt) b0[nt] = *(const short8*)(sb + boff[nt] + ck0);
#pragma unroll
    for (int mt = 0; mt < 4; ++mt) a00[mt] = *(const short8*)(sb + aoff[mt] + ck0);
#pragma unroll
    for (int mt = 0; mt < 4; ++mt) a01[mt] = *(const short8*)(sb + aoff[mt + 4] + ck0);

    // cluster 1: a00 x b0 -> acc[0..3]  (kk0)
    __builtin_amdgcn_s_setprio(1);
#pragma unroll
    for (int mt = 0; mt < 4; ++mt)
#pragma unroll
      for (int nt = 0; nt < 4; ++nt)
        acc[mt][nt] = __builtin_amdgcn_mfma_f32_16x16x32_bf16(a00[mt], b0[nt], acc[mt][nt], 0, 0, 0);
    __builtin_amdgcn_s_setprio(0);

#pragma unroll
    for (int nt = 0; nt < 4; ++nt) b1[nt] = *(const short8*)(sb + boff[nt] + ck1);
#pragma unroll
    for (int mt = 0; mt < 4; ++mt) a10[mt] = *(const short8*)(sb + aoff[mt] + ck1);

    // cluster 2: a01 x b0 -> acc[4..7]  (kk0)
    __builtin_amdgcn_s_setprio(1);
#pragma unroll
    for (int mt = 0; mt < 4; ++mt)
#pragma unroll
      for (int nt = 0; nt < 4; ++nt)
        acc[mt + 4][nt] = __builtin_amdgcn_mfma_f32_16x16x32_bf16(a01[mt], b0[nt], acc[mt + 4][nt], 0, 0, 0);
    __builtin_amdgcn_s_setprio(0);

#pragma unroll
    for (int mt = 0; mt < 4; ++mt) a11[mt] = *(const short8*)(sb + aoff[mt + 4] + ck1);

    // cluster 3: a10 x b1 -> acc[0..3]  (kk1)
    __builtin_amdgcn_s_setprio(1);
#pragma unroll
    for (int mt = 0; mt < 4; ++mt)
#pragma unroll
      for (int nt = 0; nt < 4; ++nt)
        acc[mt][nt] = __builtin_amdgcn_mfma_f32_16x16x32_bf16(a10[mt], b1[nt], acc[mt][nt], 0, 0, 0);
    __builtin_amdgcn_s_setprio(0);

    // cluster 4: a11 x b1 -> acc[4..7]  (kk1)
    __builtin_amdgcn_s_setprio(1);
#pragma unroll
    for (int mt = 0; mt < 4; ++mt)
#pragma unroll
      for (int nt = 0; nt < 4; ++nt)
        acc[mt + 4][nt] = __builtin_amdgcn_mfma_f32_16x16x32_bf16(a11[mt], b1[nt], acc[mt + 4][nt], 0, 0, 0);
    __builtin_amdgcn_s_setprio(0);

    // ---- single tile-end certification: one vmcnt(0)+barrier per K=64;
    // staging was issued a whole tile ago -> drain is cheap. ----
    if (t + 1 < NTILE) {
      asm volatile("s_waitcnt vmcnt(0)" ::: "memory");
      __builtin_amdgcn_s_barrier();
      __builtin_amdgcn_sched_barrier(0);  // nothing crosses the tile boundary
    }
  }
#undef STAGE

  // epilogue: + bias, store fp32
#pragma unroll
  for (int nt = 0; nt < 4; ++nt) {
    int col = bN + wn * 64 + nt * 16 + l16;
    float bv = bias[col];
#pragma unroll
    for (int mt = 0; mt < 8; ++mt) {
      int row = bM + wm * 128 + mt * 16 + quad * 4;
#pragma unroll
      for (int r2 = 0; r2 < 4; ++r2)
        out[(size_t)(row + r2) * N_OUT + col] = acc[mt][nt][r2] + bv;
    }
  }
}

extern "C" void kernel_launch(void* const* d_in, const int* in_sizes, int n_in,
                              void* d_out, int out_size, void* d_ws, size_t ws_size,
                              hipStream_t stream) {
  const float* x      = (const float*)d_in[0];
  const float* wgt    = (const float*)d_in[1];
  const float* ld     = (const float*)d_in[2];
  const float* lup    = (const float*)d_in[3];
  const float* smooth = (const float*)d_in[4];
  const float* bias   = (const float*)d_in[5];
  float* out = (float*)d_out;

  unsigned short* Xcat = (unsigned short*)d_ws;                 // 8192*2112*2 = 34.6 MB
  unsigned short* Wcat = Xcat + (size_t)M_TOK * KC;             //  8.65 MB

  hipLaunchKernelGGL(prep_kernel, dim3(512 + N_OUT), dim3(256), 0, stream,
                     x, smooth, wgt, ld, lup, Xcat, Wcat);
  hipLaunchKernelGGL(gemm_kernel, dim3((M_TOK / 256) * (N_OUT / 256)), dim3(512), 0, stream,
                     Xcat, Wcat, bias, out);
}

// Round 8
// 203.487 us; speedup vs baseline: 1.0761x; 1.0146x over previous
//
#include <hip/hip_runtime.h>
#include <stdint.h>

// SVDQuant forward on MI355X:
//   y = Q4(x*smooth) @ Q4(Wres)^T + (x*smooth) @ lora_down @ lora_up^T + bias
// R11 structure (2 kernels):
//   K1 prep_kernel (grid 3072): 37 KiB LDS -> 4 blocks/CU (R0-R10 allocated
//     72 KiB -> 2 blocks/CU for ALL blocks incl. the LDS-free W path; that
//     occupancy cap is the suspected prep bottleneck).
//     blocks [0,1024):    8 x-rows each. Phase A: coalesced fakequant(x*smooth)
//                         -> Xcat[:,0:2048] + bf16 x_s in LDS. Phase B: rank-32
//                         MFMA t = x_s @ lora_down (A-frag row clamped l16&7;
//                         C rows 8-15 discarded) -> Xcat[:,2048:2080]; pad=0.
//     blocks [1024,3072): 1 w-row each: Wcat[:,0:2048]=fakequant(Wres),
//                         [2048:2080)=bf16(lora_up), [2080:2112)=0.
//   K2 gemm_kernel (UNCHANGED from R10, 74.2us, schedule-space exhausted):
//     out = Xcat @ Wcat^T + bias, K=2112 = 33x64. BK=64, 2x64KB dbuf, stage
//     tile t+1 at tile start, ONE vmcnt(0)+s_barrier per tile, pipelined
//     fragment clusters, 2-way-max chunk swizzle, XCD-chunked blockIdx.

typedef __attribute__((ext_vector_type(8))) short short8;
typedef __attribute__((ext_vector_type(8))) unsigned short ushort8;
typedef __attribute__((ext_vector_type(4))) unsigned short ushort4v;
typedef __attribute__((ext_vector_type(4))) float floatx4;

#define M_TOK 8192
#define K_IN  2048
#define N_OUT 2048
#define RANK  32
#define KC    2112      // 2048 quant + 32 lowrank + 32 zero pad = 33 * 64
#define NTILE 33        // K-tiles of 64
#define XS_STRIDE 2056  // LDS x_s row stride (shorts): +8 -> 4-bank row rotation
#define XROWS 8         // x-rows per prep block (was 16; 8 -> 37KiB LDS, 4 blk/CU)

// round-to-nearest-even f32 -> bf16 (finite inputs only)
__device__ __forceinline__ unsigned short f2bf(float f) {
  unsigned int u = __float_as_uint(f);
  u += 0x7fff + ((u >> 16) & 1);
  return (unsigned short)(u >> 16);
}

// fakequant 8 values held by this lane; group of 64 = 8 consecutive lanes
__device__ __forceinline__ void quant8(const float* v, unsigned short* q) {
  float amax = 0.f;
#pragma unroll
  for (int i = 0; i < 8; ++i) amax = fmaxf(amax, fabsf(v[i]));
  amax = fmaxf(amax, __shfl_xor(amax, 1, 64));
  amax = fmaxf(amax, __shfl_xor(amax, 2, 64));
  amax = fmaxf(amax, __shfl_xor(amax, 4, 64));
  float scale = fmaxf(amax / 7.0f, 1e-8f);
#pragma unroll
  for (int i = 0; i < 8; ++i) {
    float qq = rintf(v[i] / scale);   // IEEE div + RNE == jnp.round(g/scale)
    qq = fminf(fmaxf(qq, -7.f), 7.f);
    q[i] = f2bf(qq * scale);
  }
}

// ---------------- K1: fused prep --------------------------------------------
__global__ __launch_bounds__(256) void prep_kernel(const float* __restrict__ x,
                                                   const float* __restrict__ smooth,
                                                   const float* __restrict__ wgt,
                                                   const float* __restrict__ ld,
                                                   const float* __restrict__ lup,
                                                   unsigned short* __restrict__ Xcat,
                                                   unsigned short* __restrict__ Wcat) {
  __shared__ unsigned short xs[XROWS * XS_STRIDE];  // 32.9 KiB bf16 x_s
  __shared__ float red[4][XROWS][32];               // 4 KiB
  int tid = threadIdx.x;

  if (blockIdx.x >= 1024) {
    // ---- W path: one row of Wres per block (no LDS use) ----
    int row = blockIdx.x - 1024;
    const float4* wr = (const float4*)(wgt + (size_t)row * K_IN);
    float4 a0 = wr[tid * 2], a1 = wr[tid * 2 + 1];
    float v[8] = {a0.x, a0.y, a0.z, a0.w, a1.x, a1.y, a1.z, a1.w};
    ushort8 q;
    quant8(v, (unsigned short*)&q);
    *(ushort8*)(Wcat + (size_t)row * KC + tid * 8) = q;
    if (tid < 32)      Wcat[(size_t)row * KC + 2048 + tid] = f2bf(lup[row * RANK + tid]);
    else if (tid < 64) Wcat[(size_t)row * KC + 2048 + tid] = 0;
    return;
  }

  // ---- X path: 8 rows per block ----
  int rowbase = blockIdx.x * XROWS;
  int w = tid >> 6, lane = tid & 63, quad = lane >> 4, l16 = lane & 15;

  // Phase A: coalesced quantize, one row per pass (256 thr x 8 elems = 2048)
  const float4* sr = (const float4*)smooth;
  float4 s0 = sr[tid * 2], s1 = sr[tid * 2 + 1];
#pragma unroll 2
  for (int r = 0; r < XROWS; ++r) {
    const float4* xr = (const float4*)(x + (size_t)(rowbase + r) * K_IN);
    float4 a0 = xr[tid * 2], a1 = xr[tid * 2 + 1];
    float v[8] = {a0.x * s0.x, a0.y * s0.y, a0.z * s0.z, a0.w * s0.w,
                  a1.x * s1.x, a1.y * s1.y, a1.z * s1.z, a1.w * s1.w};
    ushort8 q;
    quant8(v, (unsigned short*)&q);
    *(ushort8*)(Xcat + (size_t)(rowbase + r) * KC + tid * 8) = q;
    ushort8 sb;
#pragma unroll
    for (int t = 0; t < 8; ++t) sb[t] = f2bf(v[t]);
    *(ushort8*)(xs + r * XS_STRIDE + tid * 8) = sb;
  }
  // zero pad Xcat[:, 2080:2112): rows 0..7, 16 threads x 4B per row
  if (tid < 128)
    *(unsigned int*)(Xcat + (size_t)(rowbase + (tid >> 4)) * KC + 2080 + (tid & 15) * 2) = 0u;
  __syncthreads();

  // Phase B: t = x_s @ lora_down. wave w covers k in [w*512, w*512+512).
  // A-frag row clamped to l16&7 (8 real rows); C rows 8-15 are discarded.
  floatx4 acc[2];
  acc[0] = (floatx4)0.f;
  acc[1] = (floatx4)0.f;
  int kbase = w * 512;
  int arow = (l16 & 7) * XS_STRIDE;
#pragma unroll 2
  for (int it = 0; it < 16; ++it) {
    int k = kbase + it * 32 + quad * 8;
    short8 af = *(const short8*)(xs + arow + k);
    // B-frag straight from lora_down [k][r]: B[k=quad*8+j][n=l16 (+16)]
    short8 b0, b1;
#pragma unroll
    for (int j = 0; j < 8; ++j) {
      b0[j] = (short)f2bf(ld[(size_t)(k + j) * RANK + l16]);
      b1[j] = (short)f2bf(ld[(size_t)(k + j) * RANK + 16 + l16]);
    }
    acc[0] = __builtin_amdgcn_mfma_f32_16x16x32_bf16(af, b0, acc[0], 0, 0, 0);
    acc[1] = __builtin_amdgcn_mfma_f32_16x16x32_bf16(af, b1, acc[1], 0, 0, 0);
  }
  // C layout: row = quad*4 + r, col = l16 (+16 for acc[1]); keep rows < 8
#pragma unroll
  for (int nt = 0; nt < 2; ++nt)
#pragma unroll
    for (int r = 0; r < 4; ++r) {
      int row = quad * 4 + r;
      if (row < XROWS) red[w][row][nt * 16 + l16] = acc[nt][r];
    }
  __syncthreads();
  if (tid < 64) {
    int rl = tid >> 3, seg = tid & 7;  // row 0..7, col segment of 4
    ushort4v o;
#pragma unroll
    for (int j = 0; j < 4; ++j) {
      int c = seg * 4 + j;
      float s = red[0][rl][c] + red[1][rl][c] + red[2][rl][c] + red[3][rl][c];
      o[j] = f2bf(s);
    }
    *(ushort4v*)(Xcat + (size_t)(rowbase + rl) * KC + 2048 + seg * 4) = o;
  }
}

// ---------------- K2: main GEMM: out = Xcat @ Wcat^T + bias ----------------
__device__ __forceinline__ void gld_lds16(const unsigned short* g, unsigned short* l) {
  __builtin_amdgcn_global_load_lds(
      (const __attribute__((address_space(1))) unsigned int*)g,
      (__attribute__((address_space(3))) unsigned int*)l, 16, 0, 0);
}

__global__ __launch_bounds__(512) void gemm_kernel(const unsigned short* __restrict__ Xcat,
                                                   const unsigned short* __restrict__ Wcat,
                                                   const float* __restrict__ bias,
                                                   float* __restrict__ out) {
  // 2 K-tile buffers x (A 256x64 + B 256x64) bf16 = 128 KiB, 1 block/CU
  __shared__ unsigned short smem[65536];
  int tid = threadIdx.x;
  int w = tid >> 6, lane = tid & 63, quad = lane >> 4, l16 = lane & 15;
  int wm = w >> 2, wn = w & 3;  // 2 M-waves x 4 N-waves; wave tile 128x64

  // Bijective XCD chunking: grid 256 = 8 XCDs x 32; each XCD gets a contiguous
  // chunk = 4 M-panels x 8 N-panels -> A/B panel slabs stay L2-resident.
  int bid = blockIdx.x;
  int wg = (bid & 7) * 32 + (bid >> 3);
  int bM = (wg >> 3) * 256;
  int bN = (wg & 7) * 256;

  // Staging: per K-tile, A = 256 rows x 8 chunks(16B) = 32KB (same B), 4 slices
  // of 64 rows each. thread covers (row = 64*i + tid/8, chunk slot = tid&7);
  // source chunk pre-swizzled with row&7 == (tid>>3)&7 so swizzled reads match.
  int srow = tid >> 3;                  // 0..63
  int csrc = (tid & 7) ^ (srow & 7);
  const unsigned short* Ag = Xcat + (size_t)(bM + srow) * KC + csrc * 8;
  const unsigned short* Bg = Wcat + (size_t)(bN + srow) * KC + csrc * 8;
  int ldsrow = w * 512;                 // wave-uniform dest: w*8 rows * 64 shorts

#define STAGE(tt, OFF)                                                        \
  do {                                                                        \
    int k0_ = (tt) * 64;                                                      \
    gld_lds16(Ag + k0_,            smem + (OFF) + ldsrow);                    \
    gld_lds16(Ag + 64 * KC + k0_,  smem + (OFF) + 4096 + ldsrow);             \
    gld_lds16(Ag + 128 * KC + k0_, smem + (OFF) + 8192 + ldsrow);             \
    gld_lds16(Ag + 192 * KC + k0_, smem + (OFF) + 12288 + ldsrow);            \
    gld_lds16(Bg + k0_,            smem + (OFF) + 16384 + ldsrow);            \
    gld_lds16(Bg + 64 * KC + k0_,  smem + (OFF) + 20480 + ldsrow);            \
    gld_lds16(Bg + 128 * KC + k0_, smem + (OFF) + 24576 + ldsrow);            \
    gld_lds16(Bg + 192 * KC + k0_, smem + (OFF) + 28672 + ldsrow);            \
  } while (0)

  // fragment LDS offsets (shorts): row*64 + swizzled chunk; row&7 == l16&7.
  int l7 = l16 & 7;
  int ck0 = (quad ^ l7) * 8;            // kk = 0 chunk (global chunks 0-3)
  int ck1 = ((4 + quad) ^ l7) * 8;      // kk = 1 chunk (global chunks 4-7)
  int aoff[8], boff[4];
#pragma unroll
  for (int mt = 0; mt < 8; ++mt) aoff[mt] = (wm * 128 + mt * 16 + l16) * 64;
#pragma unroll
  for (int nt = 0; nt < 4; ++nt) boff[nt] = 16384 + (wn * 64 + nt * 16 + l16) * 64;

  floatx4 acc[8][4];
#pragma unroll
  for (int mt = 0; mt < 8; ++mt)
#pragma unroll
    for (int nt = 0; nt < 4; ++nt) acc[mt][nt] = (floatx4)0.f;

  // prologue: stage tile 0, certify, go
  STAGE(0, 0);
  asm volatile("s_waitcnt vmcnt(0)" ::: "memory");
  __builtin_amdgcn_s_barrier();

#pragma unroll 1
  for (int t = 0; t < NTILE; ++t) {
    unsigned short* sb = smem + (t & 1) * 32768;

    // issue tile t+1's staging first: full tile of latency cover; target
    // buffer was freed by the previous tile-end barrier.
    if (t + 1 < NTILE) STAGE(t + 1, ((t + 1) & 1) * 32768);

    short8 b0[4], b1[4], a00[4], a01[4], a10[4], a11[4];

    // ---- pipelined clusters: reads for cluster g+1 issue BEFORE cluster g's
    // MFMA burst, so ds_read service hides under the matrix pipe. ----
#pragma unroll
    for (int nt = 0; nt < 4; ++nt) b0[nt] = *(const short8*)(sb + boff[nt] + ck0);
#pragma unroll
    for (int mt = 0; mt < 4; ++mt) a00[mt] = *(const short8*)(sb + aoff[mt] + ck0);
#pragma unroll
    for (int mt = 0; mt < 4; ++mt) a01[mt] = *(const short8*)(sb + aoff[mt + 4] + ck0);

    // cluster 1: a00 x b0 -> acc[0..3]  (kk0)
    __builtin_amdgcn_s_setprio(1);
#pragma unroll
    for (int mt = 0; mt < 4; ++mt)
#pragma unroll
      for (int nt = 0; nt < 4; ++nt)
        acc[mt][nt] = __builtin_amdgcn_mfma_f32_16x16x32_bf16(a00[mt], b0[nt], acc[mt][nt], 0, 0, 0);
    __builtin_amdgcn_s_setprio(0);

#pragma unroll
    for (int nt = 0; nt < 4; ++nt) b1[nt] = *(const short8*)(sb + boff[nt] + ck1);
#pragma unroll
    for (int mt = 0; mt < 4; ++mt) a10[mt] = *(const short8*)(sb + aoff[mt] + ck1);

    // cluster 2: a01 x b0 -> acc[4..7]  (kk0)
    __builtin_amdgcn_s_setprio(1);
#pragma unroll
    for (int mt = 0; mt < 4; ++mt)
#pragma unroll
      for (int nt = 0; nt < 4; ++nt)
        acc[mt + 4][nt] = __builtin_amdgcn_mfma_f32_16x16x32_bf16(a01[mt], b0[nt], acc[mt + 4][nt], 0, 0, 0);
    __builtin_amdgcn_s_setprio(0);

#pragma unroll
    for (int mt = 0; mt < 4; ++mt) a11[mt] = *(const short8*)(sb + aoff[mt + 4] + ck1);

    // cluster 3: a10 x b1 -> acc[0..3]  (kk1)
    __builtin_amdgcn_s_setprio(1);
#pragma unroll
    for (int mt = 0; mt < 4; ++mt)
#pragma unroll
      for (int nt = 0; nt < 4; ++nt)
        acc[mt][nt] = __builtin_amdgcn_mfma_f32_16x16x32_bf16(a10[mt], b1[nt], acc[mt][nt], 0, 0, 0);
    __builtin_amdgcn_s_setprio(0);

    // cluster 4: a11 x b1 -> acc[4..7]  (kk1)
    __builtin_amdgcn_s_setprio(1);
#pragma unroll
    for (int mt = 0; mt < 4; ++mt)
#pragma unroll
      for (int nt = 0; nt < 4; ++nt)
        acc[mt + 4][nt] = __builtin_amdgcn_mfma_f32_16x16x32_bf16(a11[mt], b1[nt], acc[mt + 4][nt], 0, 0, 0);
    __builtin_amdgcn_s_setprio(0);

    // ---- single tile-end certification: one vmcnt(0)+barrier per K=64;
    // staging was issued a whole tile ago -> drain is cheap. ----
    if (t + 1 < NTILE) {
      asm volatile("s_waitcnt vmcnt(0)" ::: "memory");
      __builtin_amdgcn_s_barrier();
      __builtin_amdgcn_sched_barrier(0);  // nothing crosses the tile boundary
    }
  }
#undef STAGE

  // epilogue: + bias, store fp32
#pragma unroll
  for (int nt = 0; nt < 4; ++nt) {
    int col = bN + wn * 64 + nt * 16 + l16;
    float bv = bias[col];
#pragma unroll
    for (int mt = 0; mt < 8; ++mt) {
      int row = bM + wm * 128 + mt * 16 + quad * 4;
#pragma unroll
      for (int r2 = 0; r2 < 4; ++r2)
        out[(size_t)(row + r2) * N_OUT + col] = acc[mt][nt][r2] + bv;
    }
  }
}

extern "C" void kernel_launch(void* const* d_in, const int* in_sizes, int n_in,
                              void* d_out, int out_size, void* d_ws, size_t ws_size,
                              hipStream_t stream) {
  const float* x      = (const float*)d_in[0];
  const float* wgt    = (const float*)d_in[1];
  const float* ld     = (const float*)d_in[2];
  const float* lup    = (const float*)d_in[3];
  const float* smooth = (const float*)d_in[4];
  const float* bias   = (const float*)d_in[5];
  float* out = (float*)d_out;

  unsigned short* Xcat = (unsigned short*)d_ws;                 // 8192*2112*2 = 34.6 MB
  unsigned short* Wcat = Xcat + (size_t)M_TOK * KC;             //  8.65 MB

  hipLaunchKernelGGL(prep_kernel, dim3(1024 + N_OUT), dim3(256), 0, stream,
                     x, smooth, wgt, ld, lup, Xcat, Wcat);
  hipLaunchKernelGGL(gemm_kernel, dim3((M_TOK / 256) * (N_OUT / 256)), dim3(512), 0, stream,
                     Xcat, Wcat, bias, out);
}